// Round 1
// baseline (343.338 us; speedup 1.0000x reference)
//
#include <hip/hip_runtime.h>
#include <cmath>

#define LL 2048
#define NROW 8192
#define DMODEL 1024
#define DINNER 2048
#define NSTATE 16
#define NSEG 64
#define SEGLEN 32   // NSEG * SEGLEN == LL

typedef unsigned short u16;
typedef __attribute__((ext_vector_type(8))) unsigned short u16x8;
typedef __attribute__((ext_vector_type(8))) short short8;
typedef __attribute__((ext_vector_type(4))) float floatx4;
typedef __attribute__((ext_vector_type(16))) float floatx16;

__device__ __forceinline__ float bf2f(u16 h) {
    unsigned u = ((unsigned)h) << 16;
    float f;
    __builtin_memcpy(&f, &u, 4);
    return f;
}
__device__ __forceinline__ u16 f2bf(float f) {
    unsigned u;
    __builtin_memcpy(&u, &f, 4);
    u = u + 0x7fffu + ((u >> 16) & 1u);
    return (u16)(u >> 16);
}
__device__ __forceinline__ float silu_f(float x) { return x / (1.f + __expf(-x)); }

// One kernel converts all six fp32->bf16 tensors (2048 elems per block).
__global__ __launch_bounds__(256) void cvt_multi(
    const float* __restrict__ s0, const float* __restrict__ s1,
    const float* __restrict__ s2, const float* __restrict__ s3,
    const float* __restrict__ s4, const float* __restrict__ s5,
    u16* __restrict__ d0, u16* __restrict__ d1, u16* __restrict__ d2,
    u16* __restrict__ d3, u16* __restrict__ d4, u16* __restrict__ d5) {
    int bid = blockIdx.x;
    const float* s;
    u16* d;
    size_t off;
    if (bid < 4096)      { s = s0; d = d0; off = (size_t)bid * 2048; }
    else if (bid < 6144) { s = s1; d = d1; off = (size_t)(bid - 4096) * 2048; }
    else if (bid < 7168) { s = s2; d = d2; off = (size_t)(bid - 6144) * 2048; }
    else if (bid < 7184) { s = s3; d = d3; off = (size_t)(bid - 7168) * 2048; }
    else if (bid < 7200) { s = s4; d = d4; off = (size_t)(bid - 7184) * 2048; }
    else                 { s = s5; d = d5; off = (size_t)(bid - 7200) * 2048; }
    size_t i = off + (size_t)threadIdx.x * 8;
    float4 a = *(const float4*)&s[i];
    float4 b = *(const float4*)&s[i + 4];
    u16x8 o;
    o[0] = f2bf(a.x); o[1] = f2bf(a.y); o[2] = f2bf(a.z); o[3] = f2bf(a.w);
    o[4] = f2bf(b.x); o[5] = f2bf(b.y); o[6] = f2bf(b.z); o[7] = f2bf(b.w);
    *(u16x8*)&d[i] = o;
}

// ---------------------------------------------------------------------------
// 256x256 deep-phased GEMM (C = A @ B^T), A: MxK bf16, B: NxK bf16 row-major.
// BK=64 split into two [256][32] k-half LDS tiles (k-slot XOR swizzle
// kb^((row>>1)&3), identical to the verified 128^2 kernel's pattern).
// 8 waves (2M x 4N), per-wave C 128x64 as 8x4 16x16x32 frags. Double-buffered
// 128 KiB LDS, 4 phases per K-tile, counted vmcnt(4) at phase-2/4 ends only
// (never 0 in the loop), raw s_barrier + lgkmcnt(0) + setprio around MFMA.
// vmcnt account (issue order per tile: A0,B0,A1,B1, 2 loads each):
//   ph2-end vmcnt(4): newest 4 = A0,B0(t+1) -> A1,B1(t) landed (ph3/4 reads ok)
//   ph4-end vmcnt(4): newest 4 = A1,B1(t+1) -> A0,B0(t+1) landed (ph1/2 ok)
// Last iteration re-stages tile 0 (keeps count discipline; writes unread buf).
// ---------------------------------------------------------------------------
template <int OUT_BF16>
__global__ __launch_bounds__(512, 2) void gemm_bt_256(
    const u16* __restrict__ A, const u16* __restrict__ B,
    void* __restrict__ Cout, int N, int K) {
    __shared__ u16 sA[2][2][256 * 32];   // [buf][khalf][row*32 + slot*8]
    __shared__ u16 sB[2][2][256 * 32];
    const int tid = threadIdx.x;
    const int lane = tid & 63;
    const int wave = tid >> 6;     // 0..7
    const int wm = wave >> 2;      // 0..1  (M half)
    const int wn = wave & 3;       // 0..3  (N quarter)
    const int bm = blockIdx.y * 256;
    const int bn = blockIdx.x * 256;

    // staging: each wave stages chunks {wave*2, wave*2+1} (16 rows each) of a
    // [256][32] half-tile per issue pair; lane writes 16B at lane*16 ->
    // row = chunk*16 + (lane>>2), slot = lane&3, so source k-block must be
    // pre-swizzled: kbg = (lane&3) ^ ((lane>>3)&3).
    const int srow = lane >> 2;
    const int kbg = (lane & 3) ^ ((lane >> 3) & 3);
    const u16* aBase[2];
    const u16* bBase[2];
#pragma unroll
    for (int p = 0; p < 2; ++p) {
        int chunk = wave * 2 + p;
        aBase[p] = A + (size_t)(bm + chunk * 16 + srow) * K + kbg * 8;
        bBase[p] = B + (size_t)(bn + chunk * 16 + srow) * K + kbg * 8;
    }
    const int ldsOff[2] = {(wave * 2) * 512, (wave * 2 + 1) * 512};

    auto stageA = [&](int buf, int kh, int kt) {
#pragma unroll
        for (int p = 0; p < 2; ++p)
            __builtin_amdgcn_global_load_lds(
                (const __attribute__((address_space(1))) void*)(aBase[p] + kt * 64 + kh * 32),
                (__attribute__((address_space(3))) void*)&sA[buf][kh][ldsOff[p]], 16, 0, 0);
    };
    auto stageB = [&](int buf, int kh, int kt) {
#pragma unroll
        for (int p = 0; p < 2; ++p)
            __builtin_amdgcn_global_load_lds(
                (const __attribute__((address_space(1))) void*)(bBase[p] + kt * 64 + kh * 32),
                (__attribute__((address_space(3))) void*)&sB[buf][kh][ldsOff[p]], 16, 0, 0);
    };

    // fragment offsets: row R = base + fr, k-block kq = lane>>4,
    // stored slot = kq ^ ((R>>1)&3) = kq ^ ((fr>>1)&3)   (bases are mult of 16)
    const int fr = lane & 15;
    const int kq = lane >> 4;
    const int ks2 = kq ^ ((fr >> 1) & 3);
    int aoff[2][4], boff[4];
#pragma unroll
    for (int qm = 0; qm < 2; ++qm)
#pragma unroll
        for (int mi = 0; mi < 4; ++mi)
            aoff[qm][mi] = (wm * 128 + qm * 64 + mi * 16 + fr) * 32 + ks2 * 8;
#pragma unroll
    for (int ni = 0; ni < 4; ++ni)
        boff[ni] = (wn * 64 + ni * 16 + fr) * 32 + ks2 * 8;

    floatx4 acc[8][4];
#pragma unroll
    for (int i = 0; i < 8; ++i)
#pragma unroll
        for (int j = 0; j < 4; ++j) acc[i][j] = (floatx4){0.f, 0.f, 0.f, 0.f};

    // prologue: stage tile 0 fully, drain once, barrier.
    stageA(0, 0, 0);
    stageB(0, 0, 0);
    stageA(0, 1, 0);
    stageB(0, 1, 0);
    asm volatile("s_waitcnt vmcnt(0)" ::: "memory");
    __builtin_amdgcn_s_barrier();

    const int NT = K >> 6;
    for (int t = 0; t < NT; ++t) {
        const int cur = t & 1;
        const int nxt = cur ^ 1;
        int tn = t + 1;
        if (tn == NT) tn = 0;  // wrap: keeps vmcnt discipline, no OOB
        short8 af[4], bf[4];

        // ---- phase 1: (qm=0, ks=0) ----
#pragma unroll
        for (int mi = 0; mi < 4; ++mi) af[mi] = *(const short8*)&sA[cur][0][aoff[0][mi]];
#pragma unroll
        for (int ni = 0; ni < 4; ++ni) bf[ni] = *(const short8*)&sB[cur][0][boff[ni]];
        stageA(nxt, 0, tn);
        __builtin_amdgcn_s_barrier();
        asm volatile("s_waitcnt lgkmcnt(0)" ::: "memory");
        __builtin_amdgcn_s_setprio(1);
#pragma unroll
        for (int mi = 0; mi < 4; ++mi)
#pragma unroll
            for (int ni = 0; ni < 4; ++ni)
                acc[mi][ni] = __builtin_amdgcn_mfma_f32_16x16x32_bf16(af[mi], bf[ni],
                                                                      acc[mi][ni], 0, 0, 0);
        __builtin_amdgcn_s_setprio(0);
        __builtin_amdgcn_s_barrier();

        // ---- phase 2: (qm=1, ks=0), reuse bf ----
#pragma unroll
        for (int mi = 0; mi < 4; ++mi) af[mi] = *(const short8*)&sA[cur][0][aoff[1][mi]];
        stageB(nxt, 0, tn);
        __builtin_amdgcn_s_barrier();
        asm volatile("s_waitcnt lgkmcnt(0)" ::: "memory");
        __builtin_amdgcn_s_setprio(1);
#pragma unroll
        for (int mi = 0; mi < 4; ++mi)
#pragma unroll
            for (int ni = 0; ni < 4; ++ni)
                acc[4 + mi][ni] = __builtin_amdgcn_mfma_f32_16x16x32_bf16(af[mi], bf[ni],
                                                                          acc[4 + mi][ni], 0, 0, 0);
        __builtin_amdgcn_s_setprio(0);
        asm volatile("s_waitcnt vmcnt(4)" ::: "memory");
        __builtin_amdgcn_s_barrier();
        __builtin_amdgcn_sched_barrier(0);

        // ---- phase 3: (qm=0, ks=1) ----
#pragma unroll
        for (int mi = 0; mi < 4; ++mi) af[mi] = *(const short8*)&sA[cur][1][aoff[0][mi]];
#pragma unroll
        for (int ni = 0; ni < 4; ++ni) bf[ni] = *(const short8*)&sB[cur][1][boff[ni]];
        stageA(nxt, 1, tn);
        __builtin_amdgcn_s_barrier();
        asm volatile("s_waitcnt lgkmcnt(0)" ::: "memory");
        __builtin_amdgcn_s_setprio(1);
#pragma unroll
        for (int mi = 0; mi < 4; ++mi)
#pragma unroll
            for (int ni = 0; ni < 4; ++ni)
                acc[mi][ni] = __builtin_amdgcn_mfma_f32_16x16x32_bf16(af[mi], bf[ni],
                                                                      acc[mi][ni], 0, 0, 0);
        __builtin_amdgcn_s_setprio(0);
        __builtin_amdgcn_s_barrier();

        // ---- phase 4: (qm=1, ks=1), reuse bf ----
#pragma unroll
        for (int mi = 0; mi < 4; ++mi) af[mi] = *(const short8*)&sA[cur][1][aoff[1][mi]];
        stageB(nxt, 1, tn);
        __builtin_amdgcn_s_barrier();
        asm volatile("s_waitcnt lgkmcnt(0)" ::: "memory");
        __builtin_amdgcn_s_setprio(1);
#pragma unroll
        for (int mi = 0; mi < 4; ++mi)
#pragma unroll
            for (int ni = 0; ni < 4; ++ni)
                acc[4 + mi][ni] = __builtin_amdgcn_mfma_f32_16x16x32_bf16(af[mi], bf[ni],
                                                                          acc[4 + mi][ni], 0, 0, 0);
        __builtin_amdgcn_s_setprio(0);
        asm volatile("s_waitcnt vmcnt(4)" ::: "memory");
        __builtin_amdgcn_s_barrier();
        __builtin_amdgcn_sched_barrier(0);
    }

    // epilogue: C/D 16x16 layout: col = lane&15, row = (lane>>4)*4 + r
    const int cc = lane & 15;
    const int rb = (lane >> 4) * 4;
#pragma unroll
    for (int mi = 0; mi < 8; ++mi)
#pragma unroll
        for (int ni = 0; ni < 4; ++ni)
#pragma unroll
            for (int r = 0; r < 4; ++r) {
                int grow = bm + wm * 128 + mi * 16 + rb + r;
                int gcol = bn + wn * 64 + ni * 16 + cc;
                float v = acc[mi][ni][r];
                if (OUT_BF16)
                    ((u16*)Cout)[(size_t)grow * N + gcol] = f2bf(v);
                else
                    ((float*)Cout)[(size_t)grow * N + gcol] = v;
            }
}

// C[m][n] = sum_k A[m,k]*B[n,k]; A: MxK bf16, B: NxK bf16, row-major.
// 128x128 tile, BK=32, 4 waves (2x2), each wave 64x64 via 2x2 of 32x32x16 MFMA
// (2 K-steps per BK). Kept for the thin out-proj GEMM (N=1024: 512 blocks).
template <int OUT_BF16>
__global__ __launch_bounds__(256) void gemm_bt_mfma(
    const u16* __restrict__ A, const u16* __restrict__ B,
    void* __restrict__ Cout, int N, int K) {
    __shared__ u16 As[128 * 32];
    __shared__ u16 Bs[128 * 32];
    const int tid = threadIdx.x;
    const int lane = tid & 63;
    const int wave = tid >> 6;
    const int bm = blockIdx.y * 128;
    const int bn = blockIdx.x * 128;

    const int kbg = (lane & 3) ^ ((lane >> 3) & 3);
    const int srow = lane >> 2;
    const u16* ag[2];
    const u16* bg[2];
#pragma unroll
    for (int p = 0; p < 2; ++p) {
        int c = wave * 2 + p;
        ag[p] = A + (size_t)(bm + c * 16 + srow) * K + kbg * 8;
        bg[p] = B + (size_t)(bn + c * 16 + srow) * K + kbg * 8;
    }
    const int frow = lane & 31;
    const int khi = lane >> 5;
    const int wr = (wave >> 1) * 64;
    const int wc = (wave & 1) * 64;
    int aoff[2][2], boff[2][2];
#pragma unroll
    for (int mi = 0; mi < 2; ++mi)
#pragma unroll
        for (int kh = 0; kh < 2; ++kh) {
            int rA = wr + mi * 32 + frow;
            int rB = wc + mi * 32 + frow;
            int kb = kh * 2 + khi;
            aoff[mi][kh] = rA * 32 + (kb ^ ((rA >> 1) & 3)) * 8;
            boff[mi][kh] = rB * 32 + (kb ^ ((rB >> 1) & 3)) * 8;
        }
    floatx16 acc[2][2];
#pragma unroll
    for (int i = 0; i < 2; ++i)
#pragma unroll
        for (int j = 0; j < 2; ++j) acc[i][j] = (floatx16)(0.f);

    for (int k0 = 0; k0 < K; k0 += 32) {
        __syncthreads();
#pragma unroll
        for (int p = 0; p < 2; ++p) {
            int c = wave * 2 + p;
            __builtin_amdgcn_global_load_lds(
                (const __attribute__((address_space(1))) void*)ag[p],
                (__attribute__((address_space(3))) void*)&As[c * 512], 16, 0, 0);
            __builtin_amdgcn_global_load_lds(
                (const __attribute__((address_space(1))) void*)bg[p],
                (__attribute__((address_space(3))) void*)&Bs[c * 512], 16, 0, 0);
            ag[p] += 32;
            bg[p] += 32;
        }
        __syncthreads();
        short8 af[2][2], bf[2][2];
#pragma unroll
        for (int mi = 0; mi < 2; ++mi)
#pragma unroll
            for (int kh = 0; kh < 2; ++kh) {
                af[mi][kh] = *(const short8*)&As[aoff[mi][kh]];
                bf[mi][kh] = *(const short8*)&Bs[boff[mi][kh]];
            }
#pragma unroll
        for (int kh = 0; kh < 2; ++kh)
#pragma unroll
            for (int mi = 0; mi < 2; ++mi)
#pragma unroll
                for (int ni = 0; ni < 2; ++ni)
                    acc[mi][ni] = __builtin_amdgcn_mfma_f32_32x32x16_bf16(
                        af[mi][kh], bf[ni][kh], acc[mi][ni], 0, 0, 0);
    }
    // C/D layout (m74/m101): col = lane&31, row = (reg&3) + 8*(reg>>2) + 4*(lane>>5)
    const int cc = lane & 31;
    const int rbase = 4 * (lane >> 5);
#pragma unroll
    for (int mi = 0; mi < 2; ++mi)
#pragma unroll
        for (int ni = 0; ni < 2; ++ni)
#pragma unroll
            for (int r = 0; r < 16; ++r) {
                int grow = bm + wr + mi * 32 + (r & 3) + 8 * (r >> 2) + rbase;
                int gcol = bn + wc + ni * 32 + cc;
                float v = acc[mi][ni][r];
                if (OUT_BF16)
                    ((u16*)Cout)[(size_t)grow * N + gcol] = f2bf(v);
                else
                    ((float*)Cout)[(size_t)grow * N + gcol] = v;
            }
}

// depthwise causal conv (DC=4) + bias + silu + row-mean.
__global__ __launch_bounds__(256) void conv_silu_avg(
    const u16* __restrict__ xin, const float* __restrict__ cw,
    const float* __restrict__ cb, u16* __restrict__ xconv,
    float* __restrict__ xavg) {
    const int blk = blockIdx.x;        // 512 blocks
    const int b = blk >> 7;
    const int lc = blk & 127;
    const int row0 = b * LL + lc * 16;
    const int tid = threadIdx.x;
    const int lane = tid & 63, wave = tid >> 6;
    const int d0 = tid * 8;
    float4 cwv[8];
    float cbv[8];
#pragma unroll
    for (int e = 0; e < 8; ++e) cwv[e] = *(const float4*)&cw[(d0 + e) * 4];
#pragma unroll
    for (int e = 0; e < 8; e += 4) {
        float4 c = *(const float4*)&cb[d0 + e];
        cbv[e] = c.x; cbv[e + 1] = c.y; cbv[e + 2] = c.z; cbv[e + 3] = c.w;
    }
    u16x8 w0, w1, w2;
    if (lc == 0) {
        w0 = (u16x8)0; w1 = (u16x8)0; w2 = (u16x8)0;
    } else {
        w0 = *(const u16x8*)&xin[(size_t)(row0 - 3) * (2 * DINNER) + d0];
        w1 = *(const u16x8*)&xin[(size_t)(row0 - 2) * (2 * DINNER) + d0];
        w2 = *(const u16x8*)&xin[(size_t)(row0 - 1) * (2 * DINNER) + d0];
    }
    float sums[16];
#pragma unroll
    for (int t = 0; t < 16; ++t) {
        u16x8 cur = *(const u16x8*)&xin[(size_t)(row0 + t) * (2 * DINNER) + d0];
        float lsum = 0.f;
        u16x8 o;
#pragma unroll
        for (int e = 0; e < 8; ++e) {
            float acc = cbv[e];
            acc += bf2f(w0[e]) * cwv[e].x;
            acc += bf2f(w1[e]) * cwv[e].y;
            acc += bf2f(w2[e]) * cwv[e].z;
            acc += bf2f(cur[e]) * cwv[e].w;
            float s = silu_f(acc);
            lsum += s;
            o[e] = f2bf(s);
        }
        *(u16x8*)&xconv[(size_t)(row0 + t) * DINNER + d0] = o;
        sums[t] = lsum;
        w0 = w1; w1 = w2; w2 = cur;
    }
#pragma unroll
    for (int off = 32; off; off >>= 1)
#pragma unroll
        for (int t = 0; t < 16; ++t) sums[t] += __shfl_down(sums[t], off);
    __shared__ float wred[4][16];
    if (lane == 0) {
#pragma unroll
        for (int t = 0; t < 16; ++t) wred[wave][t] = sums[t];
    }
    __syncthreads();
    if (tid < 16)
        xavg[row0 + tid] = (wred[0][tid] + wred[1][tid] + wred[2][tid] + wred[3][tid]) *
                           (1.f / DINNER);
}

// delta/B/C projections via MFMA (16x16x32): thin GEMM (8192 x 48 x 2048).
__global__ __launch_bounds__(256) void dbc_mfma(
    const u16* __restrict__ xconv, const u16* __restrict__ wcat,
    const float* __restrict__ db, const float* __restrict__ A_log,
    const float* __restrict__ xavg,
    float* __restrict__ a_out, float* __restrict__ u_out, float* __restrict__ c_out) {
    __shared__ u16 As[128 * 32];
    __shared__ u16 Bs[48 * 32];
    const int tid = threadIdx.x;
    const int lane = tid & 63;
    const int wave = tid >> 6;
    const int bm = blockIdx.x * 128;

    const int kbg = (lane & 3) ^ ((lane >> 3) & 3);
    const int srow = lane >> 2;
    const u16* ag[2];
#pragma unroll
    for (int p = 0; p < 2; ++p) {
        int c = wave * 2 + p;
        ag[p] = xconv + (size_t)(bm + c * 16 + srow) * DINNER + kbg * 8;
    }
    const u16* bgp = wcat + (size_t)(wave * 16 + srow) * DINNER + kbg * 8;  // wave<3 only
    const int fr = lane & 15;
    const int kb = lane >> 4;
    const int kbs = kb ^ ((fr >> 1) & 3);
    int aoff[2], boff[3];
#pragma unroll
    for (int mi = 0; mi < 2; ++mi) aoff[mi] = (wave * 32 + mi * 16 + fr) * 32 + kbs * 8;
#pragma unroll
    for (int ni = 0; ni < 3; ++ni) boff[ni] = (ni * 16 + fr) * 32 + kbs * 8;

    floatx4 acc[2][3];
#pragma unroll
    for (int mi = 0; mi < 2; ++mi)
#pragma unroll
        for (int ni = 0; ni < 3; ++ni) acc[mi][ni] = (floatx4){0.f, 0.f, 0.f, 0.f};

    for (int k0 = 0; k0 < DINNER; k0 += 32) {
        __syncthreads();
#pragma unroll
        for (int p = 0; p < 2; ++p) {
            int c = wave * 2 + p;
            __builtin_amdgcn_global_load_lds(
                (const __attribute__((address_space(1))) void*)ag[p],
                (__attribute__((address_space(3))) void*)&As[c * 512], 16, 0, 0);
            ag[p] += 32;
        }
        if (wave < 3) {
            __builtin_amdgcn_global_load_lds(
                (const __attribute__((address_space(1))) void*)bgp,
                (__attribute__((address_space(3))) void*)&Bs[wave * 512], 16, 0, 0);
            bgp += 32;
        }
        __syncthreads();
        short8 af[2], bf[3];
#pragma unroll
        for (int mi = 0; mi < 2; ++mi) af[mi] = *(const short8*)&As[aoff[mi]];
#pragma unroll
        for (int ni = 0; ni < 3; ++ni) bf[ni] = *(const short8*)&Bs[boff[ni]];
#pragma unroll
        for (int mi = 0; mi < 2; ++mi)
#pragma unroll
            for (int ni = 0; ni < 3; ++ni)
                acc[mi][ni] = __builtin_amdgcn_mfma_f32_16x16x32_bf16(af[mi], bf[ni],
                                                                      acc[mi][ni], 0, 0, 0);
    }
    const int cr = (lane >> 4) * 4;
    const int s = lane & 15;
    const float Aa = -__expf(A_log[s]);
    const float dbs = db[s];
#pragma unroll
    for (int mi = 0; mi < 2; ++mi)
#pragma unroll
        for (int r = 0; r < 4; ++r) {
            int row = bm + wave * 32 + mi * 16 + cr + r;
            float pre = acc[mi][0][r] + dbs;
            float delta = (pre > 20.f) ? pre : log1pf(__expf(pre));
            a_out[row * NSTATE + s] = __expf(delta * Aa);
            u_out[row * NSTATE + s] = delta * acc[mi][1][r] * xavg[row];
            c_out[row * NSTATE + s] = acc[mi][2][r];
        }
}

// ---- parallel linear scan, 3 phases ----
__global__ __launch_bounds__(256) void scan_p1(
    const float* __restrict__ a, const float* __restrict__ u,
    float* __restrict__ Pc, float* __restrict__ H0c) {
    int gid = blockIdx.x * 256 + threadIdx.x;
    int s = gid & 15, seg = (gid >> 4) & (NSEG - 1), b = gid >> 10;
    size_t base = (size_t)(b * LL + seg * SEGLEN) * NSTATE + s;
    float P = 1.f, h = 0.f;
#pragma unroll 8
    for (int t = 0; t < SEGLEN; ++t) {
        float av = a[base + (size_t)t * NSTATE];
        float uv = u[base + (size_t)t * NSTATE];
        h = fmaf(av, h, uv);
        P *= av;
    }
    int o = (b * NSEG + seg) * NSTATE + s;
    Pc[o] = P;
    H0c[o] = h;
}

__global__ __launch_bounds__(64) void scan_p2(
    const float* __restrict__ Pc, const float* __restrict__ H0c,
    float* __restrict__ hstart) {
    int lane = threadIdx.x;
    int b = lane >> 4, s = lane & 15;
    float h = 0.f;
#pragma unroll 8
    for (int seg = 0; seg < NSEG; ++seg) {
        int o = (b * NSEG + seg) * NSTATE + s;
        hstart[o] = h;
        h = fmaf(Pc[o], h, H0c[o]);
    }
}

__global__ __launch_bounds__(256) void scan_p3(
    const float* __restrict__ a, const float* __restrict__ u,
    const float* __restrict__ c, const float* __restrict__ hstart,
    float* __restrict__ y) {
    int gid = blockIdx.x * 256 + threadIdx.x;
    int s = gid & 15, seg = (gid >> 4) & (NSEG - 1), b = gid >> 10;
    float h = hstart[(b * NSEG + seg) * NSTATE + s];
    size_t base = (size_t)(b * LL + seg * SEGLEN) * NSTATE + s;
#pragma unroll 8
    for (int t = 0; t < SEGLEN; ++t) {
        float av = a[base + (size_t)t * NSTATE];
        float uv = u[base + (size_t)t * NSTATE];
        float cv = c[base + (size_t)t * NSTATE];
        h = fmaf(av, h, uv);
        float p = h * cv;
        p += __shfl_xor(p, 1);
        p += __shfl_xor(p, 2);
        p += __shfl_xor(p, 4);
        p += __shfl_xor(p, 8);
        if (s == 0) y[b * LL + seg * SEGLEN + t] = p;
    }
}

// y_skip = y*silu(x_gate) + x_conv*D  -> bf16
__global__ __launch_bounds__(256) void gate_skip(
    const u16* __restrict__ xin, const float* __restrict__ y,
    const float* __restrict__ Dv, const u16* __restrict__ xconv,
    u16* __restrict__ yskip) {
    size_t i = ((size_t)blockIdx.x * 256 + threadIdx.x) * 8;
    int row = (int)(i >> 11);
    int d = (int)(i & (DINNER - 1));
    u16x8 g = *(const u16x8*)&xin[(size_t)row * (2 * DINNER) + DINNER + d];
    u16x8 xc = *(const u16x8*)&xconv[i];
    float yv = y[row];
    u16x8 o;
#pragma unroll
    for (int e = 0; e < 8; ++e) {
        float gv = silu_f(bf2f(g[e]));
        float v = yv * gv + bf2f(xc[e]) * Dv[d + e];
        o[e] = f2bf(v);
    }
    *(u16x8*)&yskip[i] = o;
}

extern "C" void kernel_launch(void* const* d_in, const int* in_sizes, int n_in,
                              void* d_out, int out_size, void* d_ws, size_t ws_size,
                              hipStream_t stream) {
    const float* x       = (const float*)d_in[0];
    const float* w_in    = (const float*)d_in[1];
    const float* conv_w  = (const float*)d_in[2];
    const float* conv_b  = (const float*)d_in[3];
    const float* A_log   = (const float*)d_in[4];
    const float* Dv      = (const float*)d_in[5];
    const float* delta_w = (const float*)d_in[6];
    const float* delta_b = (const float*)d_in[7];
    const float* B_w     = (const float*)d_in[8];
    const float* C_w     = (const float*)d_in[9];
    const float* out_w   = (const float*)d_in[10];
    float* out = (float*)d_out;

    u16* xb  = (u16*)d_ws;                 // 8192*1024
    u16* wb  = xb + 8388608;               // 4096*1024
    u16* owb = wb + 4194304;               // 1024*2048
    u16* wsb = owb + 2097152;              // 48*2048 (concat dw,bw,cw)
    u16* xin = wsb + 98304;                // 8192*4096
    u16* xcv = xin + 33554432;             // 8192*2048
    u16* ysk = xcv + 16777216;             // 8192*2048
    float* fb     = (float*)(ysk + 16777216);
    float* abuf   = fb;                    // 8192*16
    float* ubuf   = abuf + 131072;
    float* cbuf   = ubuf + 131072;
    float* pbuf   = cbuf + 131072;         // 4*64*16
    float* h0buf  = pbuf + 4096;
    float* hsbuf  = h0buf + 4096;
    float* ybuf   = hsbuf + 4096;          // 8192
    float* avgbuf = ybuf + 8192;           // 8192

    cvt_multi<<<7216, 256, 0, stream>>>(x, w_in, out_w, delta_w, B_w, C_w,
                                        xb, wb, owb, wsb, wsb + 32768, wsb + 65536);

    // x_inner = x @ in_proj_w.T : (8192x1024)@(4096x1024)^T -> bf16
    // 256^2 deep-phased kernel: grid (4096/256, 8192/256) = (16, 32)
    gemm_bt_256<1><<<dim3(16, 32), 512, 0, stream>>>(xb, wb, xin, 2 * DINNER, DMODEL);

    conv_silu_avg<<<512, 256, 0, stream>>>(xin, conv_w, conv_b, xcv, avgbuf);
    dbc_mfma<<<64, 256, 0, stream>>>(xcv, wsb, delta_b, A_log, avgbuf,
                                     abuf, ubuf, cbuf);

    scan_p1<<<16, 256, 0, stream>>>(abuf, ubuf, pbuf, h0buf);
    scan_p2<<<1, 64, 0, stream>>>(pbuf, h0buf, hsbuf);
    scan_p3<<<16, 256, 0, stream>>>(abuf, ubuf, cbuf, hsbuf, ybuf);

    gate_skip<<<NROW * DINNER / 8 / 256, 256, 0, stream>>>(xin, ybuf, Dv, xcv, ysk);

    // out = y_skip @ out_proj_w.T : (8192x2048)@(1024x2048)^T -> fp32
    gemm_bt_mfma<0><<<dim3(8, 64), 256, 0, stream>>>(ysk, owb, out, DMODEL, DINNER);
}

// Round 2
// 326.006 us; speedup vs baseline: 1.0532x; 1.0532x over previous
//
#include <hip/hip_runtime.h>
#include <cmath>

#define LL 2048
#define NROW 8192
#define DMODEL 1024
#define DINNER 2048
#define NSTATE 16
#define NSEG 64
#define SEGLEN 32   // NSEG * SEGLEN == LL

typedef unsigned short u16;
typedef __attribute__((ext_vector_type(8))) unsigned short u16x8;
typedef __attribute__((ext_vector_type(8))) short short8;
typedef __attribute__((ext_vector_type(4))) float floatx4;
typedef __attribute__((ext_vector_type(16))) float floatx16;

__device__ __forceinline__ float bf2f(u16 h) {
    unsigned u = ((unsigned)h) << 16;
    float f;
    __builtin_memcpy(&f, &u, 4);
    return f;
}
__device__ __forceinline__ u16 f2bf(float f) {
    unsigned u;
    __builtin_memcpy(&u, &f, 4);
    u = u + 0x7fffu + ((u >> 16) & 1u);
    return (u16)(u >> 16);
}
__device__ __forceinline__ float silu_f(float x) { return x / (1.f + __expf(-x)); }

// One kernel converts all six fp32->bf16 tensors (2048 elems per block).
__global__ __launch_bounds__(256) void cvt_multi(
    const float* __restrict__ s0, const float* __restrict__ s1,
    const float* __restrict__ s2, const float* __restrict__ s3,
    const float* __restrict__ s4, const float* __restrict__ s5,
    u16* __restrict__ d0, u16* __restrict__ d1, u16* __restrict__ d2,
    u16* __restrict__ d3, u16* __restrict__ d4, u16* __restrict__ d5) {
    int bid = blockIdx.x;
    const float* s;
    u16* d;
    size_t off;
    if (bid < 4096)      { s = s0; d = d0; off = (size_t)bid * 2048; }
    else if (bid < 6144) { s = s1; d = d1; off = (size_t)(bid - 4096) * 2048; }
    else if (bid < 7168) { s = s2; d = d2; off = (size_t)(bid - 6144) * 2048; }
    else if (bid < 7184) { s = s3; d = d3; off = (size_t)(bid - 7168) * 2048; }
    else if (bid < 7200) { s = s4; d = d4; off = (size_t)(bid - 7184) * 2048; }
    else                 { s = s5; d = d5; off = (size_t)(bid - 7200) * 2048; }
    size_t i = off + (size_t)threadIdx.x * 8;
    float4 a = *(const float4*)&s[i];
    float4 b = *(const float4*)&s[i + 4];
    u16x8 o;
    o[0] = f2bf(a.x); o[1] = f2bf(a.y); o[2] = f2bf(a.z); o[3] = f2bf(a.w);
    o[4] = f2bf(b.x); o[5] = f2bf(b.y); o[6] = f2bf(b.z); o[7] = f2bf(b.w);
    *(u16x8*)&d[i] = o;
}

// ---------------------------------------------------------------------------
// 256x256 pipelined GEMM (C = A @ B^T). BK=64 as two [256][32] k-half LDS
// tiles (slot XOR swizzle kb^((row>>1)&3), 0 bank conflicts verified R1).
// 8 waves (2M x 4N), per-wave C 128x64 as 8x4 16x16x32 frags.
// Read-ahead pipeline: each phase issues the NEXT phase's ds_reads into a
// pong register set before its own MFMA block, so LDS reads overlap MFMA.
// Static ping/pong parity: R1->afA,bfA  R2->afB  R3->afA,bfB  R4->afB.
// Only 2 barriers/tile, both preceded by counted vmcnt(2):
//   ph2: outstanding after wait = S1(t+1)ab -> S4(t-1) landed (R3 reads kh1 cur)
//   ph4: outstanding after wait = S3(t+1)ab -> S1,S2(t) landed (R1 reads kh0 nxt)
// All R-groups are lgkm(0)-drained before the barrier preceding the first
// overwrite of their buffer (write-after-read safe). Last tile wraps staging
// to kt=0 (keeps vmcnt discipline; the wrapped reads feed a dead MFMA phase).
// ---------------------------------------------------------------------------
#define GL_LDS(gp, lp)                                                        \
    __builtin_amdgcn_global_load_lds(                                         \
        (const __attribute__((address_space(1))) void*)(gp),                  \
        (__attribute__((address_space(3))) void*)(lp), 16, 0, 0)

template <int OUT_BF16>
__global__ __launch_bounds__(512, 2) void gemm_bt_256(
    const u16* __restrict__ A, const u16* __restrict__ B,
    void* __restrict__ Cout, int N, int K) {
    __shared__ u16 sA[2][2][256 * 32];   // [buf][khalf][row*32 + slot*8]
    __shared__ u16 sB[2][2][256 * 32];
    const int tid = threadIdx.x;
    const int lane = tid & 63;
    const int wave = tid >> 6;     // 0..7
    const int wm = wave >> 2;      // 0..1  (M half)
    const int wn = wave & 3;       // 0..3  (N quarter)
    const int bm = blockIdx.y * 256;
    const int bn = blockIdx.x * 256;

    // staging: chunk = wave*2+p covers rows [chunk*16, chunk*16+16) of a
    // [256][32] half-tile; source k-block pre-swizzled so linear LDS dest
    // lands at slot = (lane&3) ^ ((row>>1)&3) pattern. (row>>1)&3 for
    // row = chunk*16 + (lane>>2): ((lane>>3)&3) within every 16-row chunk.
    const int srow = lane >> 2;
    const int kbg = (lane & 3) ^ ((lane >> 3) & 3);
    const u16* aBase[2];
    const u16* bBase[2];
#pragma unroll
    for (int p = 0; p < 2; ++p) {
        int chunk = wave * 2 + p;
        aBase[p] = A + (size_t)(bm + chunk * 16 + srow) * K + kbg * 8;
        bBase[p] = B + (size_t)(bn + chunk * 16 + srow) * K + kbg * 8;
    }
    const int ldsOff0 = (wave * 2) * 512;
    const int ldsOff1 = (wave * 2 + 1) * 512;

#define STAGE_A(buf, kh, kt)                                                  \
    do {                                                                      \
        GL_LDS(aBase[0] + (kt) * 64 + (kh) * 32, &sA[buf][kh][ldsOff0]);      \
        GL_LDS(aBase[1] + (kt) * 64 + (kh) * 32, &sA[buf][kh][ldsOff1]);      \
    } while (0)
#define STAGE_B(buf, kh, kt)                                                  \
    do {                                                                      \
        GL_LDS(bBase[0] + (kt) * 64 + (kh) * 32, &sB[buf][kh][ldsOff0]);      \
        GL_LDS(bBase[1] + (kt) * 64 + (kh) * 32, &sB[buf][kh][ldsOff1]);      \
    } while (0)

    // fragment offsets: row R = base + fr, k-block kq = lane>>4,
    // stored slot = kq ^ ((R>>1)&3) = kq ^ ((fr>>1)&3) (bases mult of 16)
    const int fr = lane & 15;
    const int kq = lane >> 4;
    const int ks2 = kq ^ ((fr >> 1) & 3);
    int aoff[2][4], boff[4];
#pragma unroll
    for (int qm = 0; qm < 2; ++qm)
#pragma unroll
        for (int mi = 0; mi < 4; ++mi)
            aoff[qm][mi] = (wm * 128 + qm * 64 + mi * 16 + fr) * 32 + ks2 * 8;
#pragma unroll
    for (int ni = 0; ni < 4; ++ni)
        boff[ni] = (wn * 64 + ni * 16 + fr) * 32 + ks2 * 8;

#define READ_A(dst, qm, kh, buf)                                              \
    do {                                                                      \
        _Pragma("unroll")                                                     \
        for (int mi = 0; mi < 4; ++mi)                                        \
            dst[mi] = *(const short8*)&sA[buf][kh][aoff[qm][mi]];             \
    } while (0)
#define READ_B(dst, kh, buf)                                                  \
    do {                                                                      \
        _Pragma("unroll")                                                     \
        for (int ni = 0; ni < 4; ++ni)                                        \
            dst[ni] = *(const short8*)&sB[buf][kh][boff[ni]];                 \
    } while (0)
#define MFMA16(base, AF, BF)                                                  \
    do {                                                                      \
        _Pragma("unroll")                                                     \
        for (int mi = 0; mi < 4; ++mi)                                        \
            _Pragma("unroll")                                                 \
            for (int ni = 0; ni < 4; ++ni)                                    \
                acc[(base) + mi][ni] = __builtin_amdgcn_mfma_f32_16x16x32_bf16( \
                    AF[mi], BF[ni], acc[(base) + mi][ni], 0, 0, 0);           \
    } while (0)

    floatx4 acc[8][4];
#pragma unroll
    for (int i = 0; i < 8; ++i)
#pragma unroll
        for (int j = 0; j < 4; ++j) acc[i][j] = (floatx4){0.f, 0.f, 0.f, 0.f};

    short8 afA[4], afB[4], bfA[4], bfB[4];

    // prologue: stage tile 0 fully into buf0, drain, barrier, pre-read R1(0).
    STAGE_A(0, 0, 0);
    STAGE_B(0, 0, 0);
    STAGE_A(0, 1, 0);
    STAGE_B(0, 1, 0);
    asm volatile("s_waitcnt vmcnt(0)" ::: "memory");
    __builtin_amdgcn_s_barrier();
    READ_A(afA, 0, 0, 0);
    READ_B(bfA, 0, 0);
    __builtin_amdgcn_sched_barrier(0);

    const int NT = K >> 6;
    for (int t = 0; t < NT; ++t) {
        const int cur = t & 1;
        const int nxt = cur ^ 1;
        int tn = t + 1;
        if (tn == NT) tn = 0;  // wrap: keeps count discipline, no OOB

        // ---- phase 1: MFMA (qm0,kh0) with afA,bfA; read-ahead R2 ----
        asm volatile("s_waitcnt lgkmcnt(0)" ::: "memory");
        __builtin_amdgcn_sched_barrier(0);
        READ_A(afB, 1, 0, cur);          // R2: qm1 kh0 -> pong
        STAGE_A(nxt, 0, tn);             // S1(t+1)
        __builtin_amdgcn_sched_barrier(0);
        __builtin_amdgcn_s_setprio(1);
        MFMA16(0, afA, bfA);
        __builtin_amdgcn_s_setprio(0);

        // ---- phase 2: MFMA (qm1,kh0) with afB,bfA; read-ahead R3 ----
        asm volatile("s_waitcnt lgkmcnt(0)" ::: "memory");
        __builtin_amdgcn_sched_barrier(0);
        asm volatile("s_waitcnt vmcnt(2)" ::: "memory");  // S4(t-1) landed
        __builtin_amdgcn_s_barrier();
        READ_A(afA, 0, 1, cur);          // R3: qm0 kh1
        READ_B(bfB, 1, cur);             //     B  kh1
        STAGE_B(nxt, 0, tn);             // S2(t+1)
        __builtin_amdgcn_sched_barrier(0);
        __builtin_amdgcn_s_setprio(1);
        MFMA16(4, afB, bfA);
        __builtin_amdgcn_s_setprio(0);

        // ---- phase 3: MFMA (qm0,kh1) with afA,bfB; read-ahead R4 ----
        asm volatile("s_waitcnt lgkmcnt(0)" ::: "memory");
        __builtin_amdgcn_sched_barrier(0);
        READ_A(afB, 1, 1, cur);          // R4: qm1 kh1
        STAGE_A(nxt, 1, tn);             // S3(t+1)
        __builtin_amdgcn_sched_barrier(0);
        __builtin_amdgcn_s_setprio(1);
        MFMA16(0, afA, bfB);
        __builtin_amdgcn_s_setprio(0);

        // ---- phase 4: MFMA (qm1,kh1) with afB,bfB; read-ahead R1(t+1) ----
        asm volatile("s_waitcnt lgkmcnt(0)" ::: "memory");
        __builtin_amdgcn_sched_barrier(0);
        asm volatile("s_waitcnt vmcnt(2)" ::: "memory");  // S1,S2(t) landed
        __builtin_amdgcn_s_barrier();
        READ_A(afA, 0, 0, nxt);          // R1(t+1): qm0 kh0 of next buf
        READ_B(bfA, 0, nxt);
        STAGE_B(nxt, 1, tn);             // S4(t+1)
        __builtin_amdgcn_sched_barrier(0);
        __builtin_amdgcn_s_setprio(1);
        MFMA16(4, afB, bfB);
        __builtin_amdgcn_s_setprio(0);
    }

    // epilogue: C/D 16x16 layout: col = lane&15, row = (lane>>4)*4 + r
    const int cc = lane & 15;
    const int rb = (lane >> 4) * 4;
#pragma unroll
    for (int mi = 0; mi < 8; ++mi)
#pragma unroll
        for (int ni = 0; ni < 4; ++ni)
#pragma unroll
            for (int r = 0; r < 4; ++r) {
                int grow = bm + wm * 128 + mi * 16 + rb + r;
                int gcol = bn + wn * 64 + ni * 16 + cc;
                float v = acc[mi][ni][r];
                if (OUT_BF16)
                    ((u16*)Cout)[(size_t)grow * N + gcol] = f2bf(v);
                else
                    ((float*)Cout)[(size_t)grow * N + gcol] = v;
            }
#undef STAGE_A
#undef STAGE_B
#undef READ_A
#undef READ_B
#undef MFMA16
}

// C[m][n] = sum_k A[m,k]*B[n,k]; A: MxK bf16, B: NxK bf16, row-major.
// 128x128 tile, BK=32, 4 waves (2x2), each wave 64x64 via 2x2 of 32x32x16 MFMA
// (2 K-steps per BK). Kept for the thin out-proj GEMM (N=1024: 512 blocks).
template <int OUT_BF16>
__global__ __launch_bounds__(256) void gemm_bt_mfma(
    const u16* __restrict__ A, const u16* __restrict__ B,
    void* __restrict__ Cout, int N, int K) {
    __shared__ u16 As[128 * 32];
    __shared__ u16 Bs[128 * 32];
    const int tid = threadIdx.x;
    const int lane = tid & 63;
    const int wave = tid >> 6;
    const int bm = blockIdx.y * 128;
    const int bn = blockIdx.x * 128;

    const int kbg = (lane & 3) ^ ((lane >> 3) & 3);
    const int srow = lane >> 2;
    const u16* ag[2];
    const u16* bg[2];
#pragma unroll
    for (int p = 0; p < 2; ++p) {
        int c = wave * 2 + p;
        ag[p] = A + (size_t)(bm + c * 16 + srow) * K + kbg * 8;
        bg[p] = B + (size_t)(bn + c * 16 + srow) * K + kbg * 8;
    }
    const int frow = lane & 31;
    const int khi = lane >> 5;
    const int wr = (wave >> 1) * 64;
    const int wc = (wave & 1) * 64;
    int aoff[2][2], boff[2][2];
#pragma unroll
    for (int mi = 0; mi < 2; ++mi)
#pragma unroll
        for (int kh = 0; kh < 2; ++kh) {
            int rA = wr + mi * 32 + frow;
            int rB = wc + mi * 32 + frow;
            int kb = kh * 2 + khi;
            aoff[mi][kh] = rA * 32 + (kb ^ ((rA >> 1) & 3)) * 8;
            boff[mi][kh] = rB * 32 + (kb ^ ((rB >> 1) & 3)) * 8;
        }
    floatx16 acc[2][2];
#pragma unroll
    for (int i = 0; i < 2; ++i)
#pragma unroll
        for (int j = 0; j < 2; ++j) acc[i][j] = (floatx16)(0.f);

    for (int k0 = 0; k0 < K; k0 += 32) {
        __syncthreads();
#pragma unroll
        for (int p = 0; p < 2; ++p) {
            int c = wave * 2 + p;
            __builtin_amdgcn_global_load_lds(
                (const __attribute__((address_space(1))) void*)ag[p],
                (__attribute__((address_space(3))) void*)&As[c * 512], 16, 0, 0);
            __builtin_amdgcn_global_load_lds(
                (const __attribute__((address_space(1))) void*)bg[p],
                (__attribute__((address_space(3))) void*)&Bs[c * 512], 16, 0, 0);
            ag[p] += 32;
            bg[p] += 32;
        }
        __syncthreads();
        short8 af[2][2], bf[2][2];
#pragma unroll
        for (int mi = 0; mi < 2; ++mi)
#pragma unroll
            for (int kh = 0; kh < 2; ++kh) {
                af[mi][kh] = *(const short8*)&As[aoff[mi][kh]];
                bf[mi][kh] = *(const short8*)&Bs[boff[mi][kh]];
            }
#pragma unroll
        for (int kh = 0; kh < 2; ++kh)
#pragma unroll
            for (int mi = 0; mi < 2; ++mi)
#pragma unroll
                for (int ni = 0; ni < 2; ++ni)
                    acc[mi][ni] = __builtin_amdgcn_mfma_f32_32x32x16_bf16(
                        af[mi][kh], bf[ni][kh], acc[mi][ni], 0, 0, 0);
    }
    // C/D layout (m74/m101): col = lane&31, row = (reg&3) + 8*(reg>>2) + 4*(lane>>5)
    const int cc = lane & 31;
    const int rbase = 4 * (lane >> 5);
#pragma unroll
    for (int mi = 0; mi < 2; ++mi)
#pragma unroll
        for (int ni = 0; ni < 2; ++ni)
#pragma unroll
            for (int r = 0; r < 16; ++r) {
                int grow = bm + wr + mi * 32 + (r & 3) + 8 * (r >> 2) + rbase;
                int gcol = bn + wc + ni * 32 + cc;
                float v = acc[mi][ni][r];
                if (OUT_BF16)
                    ((u16*)Cout)[(size_t)grow * N + gcol] = f2bf(v);
                else
                    ((float*)Cout)[(size_t)grow * N + gcol] = v;
            }
}

// depthwise causal conv (DC=4) + bias + silu + row-mean.
__global__ __launch_bounds__(256) void conv_silu_avg(
    const u16* __restrict__ xin, const float* __restrict__ cw,
    const float* __restrict__ cb, u16* __restrict__ xconv,
    float* __restrict__ xavg) {
    const int blk = blockIdx.x;        // 512 blocks
    const int b = blk >> 7;
    const int lc = blk & 127;
    const int row0 = b * LL + lc * 16;
    const int tid = threadIdx.x;
    const int lane = tid & 63, wave = tid >> 6;
    const int d0 = tid * 8;
    float4 cwv[8];
    float cbv[8];
#pragma unroll
    for (int e = 0; e < 8; ++e) cwv[e] = *(const float4*)&cw[(d0 + e) * 4];
#pragma unroll
    for (int e = 0; e < 8; e += 4) {
        float4 c = *(const float4*)&cb[d0 + e];
        cbv[e] = c.x; cbv[e + 1] = c.y; cbv[e + 2] = c.z; cbv[e + 3] = c.w;
    }
    u16x8 w0, w1, w2;
    if (lc == 0) {
        w0 = (u16x8)0; w1 = (u16x8)0; w2 = (u16x8)0;
    } else {
        w0 = *(const u16x8*)&xin[(size_t)(row0 - 3) * (2 * DINNER) + d0];
        w1 = *(const u16x8*)&xin[(size_t)(row0 - 2) * (2 * DINNER) + d0];
        w2 = *(const u16x8*)&xin[(size_t)(row0 - 1) * (2 * DINNER) + d0];
    }
    float sums[16];
#pragma unroll
    for (int t = 0; t < 16; ++t) {
        u16x8 cur = *(const u16x8*)&xin[(size_t)(row0 + t) * (2 * DINNER) + d0];
        float lsum = 0.f;
        u16x8 o;
#pragma unroll
        for (int e = 0; e < 8; ++e) {
            float acc = cbv[e];
            acc += bf2f(w0[e]) * cwv[e].x;
            acc += bf2f(w1[e]) * cwv[e].y;
            acc += bf2f(w2[e]) * cwv[e].z;
            acc += bf2f(cur[e]) * cwv[e].w;
            float s = silu_f(acc);
            lsum += s;
            o[e] = f2bf(s);
        }
        *(u16x8*)&xconv[(size_t)(row0 + t) * DINNER + d0] = o;
        sums[t] = lsum;
        w0 = w1; w1 = w2; w2 = cur;
    }
#pragma unroll
    for (int off = 32; off; off >>= 1)
#pragma unroll
        for (int t = 0; t < 16; ++t) sums[t] += __shfl_down(sums[t], off);
    __shared__ float wred[4][16];
    if (lane == 0) {
#pragma unroll
        for (int t = 0; t < 16; ++t) wred[wave][t] = sums[t];
    }
    __syncthreads();
    if (tid < 16)
        xavg[row0 + tid] = (wred[0][tid] + wred[1][tid] + wred[2][tid] + wred[3][tid]) *
                           (1.f / DINNER);
}

// delta/B/C projections: thin GEMM (8192 x 48 x 2048), K split across waves.
// 256 blocks x 32 rows; each wave owns a K-quarter (512), frags loaded
// directly from global (L2/LLC-resident), cross-wave reduce via LDS.
__global__ __launch_bounds__(256) void dbc_direct(
    const u16* __restrict__ xconv, const u16* __restrict__ wcat,
    const float* __restrict__ db, const float* __restrict__ A_log,
    const float* __restrict__ xavg,
    float* __restrict__ a_out, float* __restrict__ u_out, float* __restrict__ c_out) {
    __shared__ float part[4][32][48];
    const int tid = threadIdx.x;
    const int lane = tid & 63;
    const int wave = tid >> 6;
    const int bm = blockIdx.x * 32;
    const int fr = lane & 15;
    const int kq = lane >> 4;
    const int k0 = wave * 512 + kq * 8;

    const u16* ap0 = xconv + (size_t)(bm + fr) * DINNER + k0;
    const u16* ap1 = xconv + (size_t)(bm + 16 + fr) * DINNER + k0;
    const u16* bp0 = wcat + (size_t)(fr) * DINNER + k0;
    const u16* bp1 = wcat + (size_t)(16 + fr) * DINNER + k0;
    const u16* bp2 = wcat + (size_t)(32 + fr) * DINNER + k0;

    floatx4 acc[2][3];
#pragma unroll
    for (int mi = 0; mi < 2; ++mi)
#pragma unroll
        for (int ni = 0; ni < 3; ++ni) acc[mi][ni] = (floatx4){0.f, 0.f, 0.f, 0.f};

#pragma unroll 4
    for (int kk = 0; kk < 16; ++kk) {
        short8 a0 = *(const short8*)ap0;
        short8 a1 = *(const short8*)ap1;
        short8 b0 = *(const short8*)bp0;
        short8 b1 = *(const short8*)bp1;
        short8 b2 = *(const short8*)bp2;
        ap0 += 32; ap1 += 32; bp0 += 32; bp1 += 32; bp2 += 32;
        acc[0][0] = __builtin_amdgcn_mfma_f32_16x16x32_bf16(a0, b0, acc[0][0], 0, 0, 0);
        acc[0][1] = __builtin_amdgcn_mfma_f32_16x16x32_bf16(a0, b1, acc[0][1], 0, 0, 0);
        acc[0][2] = __builtin_amdgcn_mfma_f32_16x16x32_bf16(a0, b2, acc[0][2], 0, 0, 0);
        acc[1][0] = __builtin_amdgcn_mfma_f32_16x16x32_bf16(a1, b0, acc[1][0], 0, 0, 0);
        acc[1][1] = __builtin_amdgcn_mfma_f32_16x16x32_bf16(a1, b1, acc[1][1], 0, 0, 0);
        acc[1][2] = __builtin_amdgcn_mfma_f32_16x16x32_bf16(a1, b2, acc[1][2], 0, 0, 0);
    }
    // C/D 16x16 layout: col = lane&15, row = (lane>>4)*4 + r
    const int cr = kq * 4;
#pragma unroll
    for (int mi = 0; mi < 2; ++mi)
#pragma unroll
        for (int ni = 0; ni < 3; ++ni)
#pragma unroll
            for (int r = 0; r < 4; ++r)
                part[wave][mi * 16 + cr + r][ni * 16 + fr] = acc[mi][ni][r];
    __syncthreads();
#pragma unroll
    for (int it = tid; it < 512; it += 256) {
        int row = it >> 4;
        int s = it & 15;
        float sd = 0.f, sb = 0.f, sc = 0.f;
#pragma unroll
        for (int w = 0; w < 4; ++w) {
            sd += part[w][row][s];
            sb += part[w][row][s + 16];
            sc += part[w][row][s + 32];
        }
        int grow = bm + row;
        float Aa = -__expf(A_log[s]);
        float pre = sd + db[s];
        float delta = (pre > 20.f) ? pre : log1pf(__expf(pre));
        a_out[grow * NSTATE + s] = __expf(delta * Aa);
        u_out[grow * NSTATE + s] = delta * sb * xavg[grow];
        c_out[grow * NSTATE + s] = sc;
    }
}

// ---- parallel linear scan, 3 phases ----
__global__ __launch_bounds__(256) void scan_p1(
    const float* __restrict__ a, const float* __restrict__ u,
    float* __restrict__ Pc, float* __restrict__ H0c) {
    int gid = blockIdx.x * 256 + threadIdx.x;
    int s = gid & 15, seg = (gid >> 4) & (NSEG - 1), b = gid >> 10;
    size_t base = (size_t)(b * LL + seg * SEGLEN) * NSTATE + s;
    float P = 1.f, h = 0.f;
#pragma unroll 8
    for (int t = 0; t < SEGLEN; ++t) {
        float av = a[base + (size_t)t * NSTATE];
        float uv = u[base + (size_t)t * NSTATE];
        h = fmaf(av, h, uv);
        P *= av;
    }
    int o = (b * NSEG + seg) * NSTATE + s;
    Pc[o] = P;
    H0c[o] = h;
}

__global__ __launch_bounds__(64) void scan_p2(
    const float* __restrict__ Pc, const float* __restrict__ H0c,
    float* __restrict__ hstart) {
    int lane = threadIdx.x;
    int b = lane >> 4, s = lane & 15;
    float h = 0.f;
#pragma unroll 8
    for (int seg = 0; seg < NSEG; ++seg) {
        int o = (b * NSEG + seg) * NSTATE + s;
        hstart[o] = h;
        h = fmaf(Pc[o], h, H0c[o]);
    }
}

__global__ __launch_bounds__(256) void scan_p3(
    const float* __restrict__ a, const float* __restrict__ u,
    const float* __restrict__ c, const float* __restrict__ hstart,
    float* __restrict__ y) {
    int gid = blockIdx.x * 256 + threadIdx.x;
    int s = gid & 15, seg = (gid >> 4) & (NSEG - 1), b = gid >> 10;
    float h = hstart[(b * NSEG + seg) * NSTATE + s];
    size_t base = (size_t)(b * LL + seg * SEGLEN) * NSTATE + s;
#pragma unroll 8
    for (int t = 0; t < SEGLEN; ++t) {
        float av = a[base + (size_t)t * NSTATE];
        float uv = u[base + (size_t)t * NSTATE];
        float cv = c[base + (size_t)t * NSTATE];
        h = fmaf(av, h, uv);
        float p = h * cv;
        p += __shfl_xor(p, 1);
        p += __shfl_xor(p, 2);
        p += __shfl_xor(p, 4);
        p += __shfl_xor(p, 8);
        if (s == 0) y[b * LL + seg * SEGLEN + t] = p;
    }
}

// y_skip = y*silu(x_gate) + x_conv*D  -> bf16
__global__ __launch_bounds__(256) void gate_skip(
    const u16* __restrict__ xin, const float* __restrict__ y,
    const float* __restrict__ Dv, const u16* __restrict__ xconv,
    u16* __restrict__ yskip) {
    size_t i = ((size_t)blockIdx.x * 256 + threadIdx.x) * 8;
    int row = (int)(i >> 11);
    int d = (int)(i & (DINNER - 1));
    u16x8 g = *(const u16x8*)&xin[(size_t)row * (2 * DINNER) + DINNER + d];
    u16x8 xc = *(const u16x8*)&xconv[i];
    float yv = y[row];
    u16x8 o;
#pragma unroll
    for (int e = 0; e < 8; ++e) {
        float gv = silu_f(bf2f(g[e]));
        float v = yv * gv + bf2f(xc[e]) * Dv[d + e];
        o[e] = f2bf(v);
    }
    *(u16x8*)&yskip[i] = o;
}

extern "C" void kernel_launch(void* const* d_in, const int* in_sizes, int n_in,
                              void* d_out, int out_size, void* d_ws, size_t ws_size,
                              hipStream_t stream) {
    const float* x       = (const float*)d_in[0];
    const float* w_in    = (const float*)d_in[1];
    const float* conv_w  = (const float*)d_in[2];
    const float* conv_b  = (const float*)d_in[3];
    const float* A_log   = (const float*)d_in[4];
    const float* Dv      = (const float*)d_in[5];
    const float* delta_w = (const float*)d_in[6];
    const float* delta_b = (const float*)d_in[7];
    const float* B_w     = (const float*)d_in[8];
    const float* C_w     = (const float*)d_in[9];
    const float* out_w   = (const float*)d_in[10];
    float* out = (float*)d_out;

    u16* xb  = (u16*)d_ws;                 // 8192*1024
    u16* wb  = xb + 8388608;               // 4096*1024
    u16* owb = wb + 4194304;               // 1024*2048
    u16* wsb = owb + 2097152;              // 48*2048 (concat dw,bw,cw)
    u16* xin = wsb + 98304;                // 8192*4096
    u16* xcv = xin + 33554432;             // 8192*2048
    u16* ysk = xcv + 16777216;             // 8192*2048
    float* fb     = (float*)(ysk + 16777216);
    float* abuf   = fb;                    // 8192*16
    float* ubuf   = abuf + 131072;
    float* cbuf   = ubuf + 131072;
    float* pbuf   = cbuf + 131072;         // 4*64*16
    float* h0buf  = pbuf + 4096;
    float* hsbuf  = h0buf + 4096;
    float* ybuf   = hsbuf + 4096;          // 8192
    float* avgbuf = ybuf + 8192;           // 8192

    cvt_multi<<<7216, 256, 0, stream>>>(x, w_in, out_w, delta_w, B_w, C_w,
                                        xb, wb, owb, wsb, wsb + 32768, wsb + 65536);

    // x_inner = x @ in_proj_w.T : (8192x1024)@(4096x1024)^T -> bf16
    gemm_bt_256<1><<<dim3(16, 32), 512, 0, stream>>>(xb, wb, xin, 2 * DINNER, DMODEL);

    conv_silu_avg<<<512, 256, 0, stream>>>(xin, conv_w, conv_b, xcv, avgbuf);
    dbc_direct<<<256, 256, 0, stream>>>(xcv, wsb, delta_b, A_log, avgbuf,
                                        abuf, ubuf, cbuf);

    scan_p1<<<16, 256, 0, stream>>>(abuf, ubuf, pbuf, h0buf);
    scan_p2<<<1, 64, 0, stream>>>(pbuf, h0buf, hsbuf);
    scan_p3<<<16, 256, 0, stream>>>(abuf, ubuf, cbuf, hsbuf, ybuf);

    gate_skip<<<NROW * DINNER / 8 / 256, 256, 0, stream>>>(xin, ybuf, Dv, xcv, ysk);

    // out = y_skip @ out_proj_w.T : (8192x2048)@(1024x2048)^T -> fp32
    gemm_bt_mfma<0><<<dim3(8, 64), 256, 0, stream>>>(ysk, owb, out, DMODEL, DINNER);
}

// Round 3
// 317.315 us; speedup vs baseline: 1.0820x; 1.0274x over previous
//
#include <hip/hip_runtime.h>
#include <cmath>

#define LL 2048
#define NROW 8192
#define DMODEL 1024
#define DINNER 2048
#define NSTATE 16
#define NSEG 64
#define SEGLEN 32   // NSEG * SEGLEN == LL

typedef unsigned short u16;
typedef __attribute__((ext_vector_type(8))) unsigned short u16x8;
typedef __attribute__((ext_vector_type(8))) short short8;
typedef __attribute__((ext_vector_type(4))) float floatx4;
typedef __attribute__((ext_vector_type(16))) float floatx16;

__device__ __forceinline__ float bf2f(u16 h) {
    unsigned u = ((unsigned)h) << 16;
    float f;
    __builtin_memcpy(&f, &u, 4);
    return f;
}
__device__ __forceinline__ u16 f2bf(float f) {
    unsigned u;
    __builtin_memcpy(&u, &f, 4);
    u = u + 0x7fffu + ((u >> 16) & 1u);
    return (u16)(u >> 16);
}
__device__ __forceinline__ float silu_f(float x) { return x / (1.f + __expf(-x)); }

// One kernel converts all six fp32->bf16 tensors (2048 elems per block).
__global__ __launch_bounds__(256) void cvt_multi(
    const float* __restrict__ s0, const float* __restrict__ s1,
    const float* __restrict__ s2, const float* __restrict__ s3,
    const float* __restrict__ s4, const float* __restrict__ s5,
    u16* __restrict__ d0, u16* __restrict__ d1, u16* __restrict__ d2,
    u16* __restrict__ d3, u16* __restrict__ d4, u16* __restrict__ d5) {
    int bid = blockIdx.x;
    const float* s;
    u16* d;
    size_t off;
    if (bid < 4096)      { s = s0; d = d0; off = (size_t)bid * 2048; }
    else if (bid < 6144) { s = s1; d = d1; off = (size_t)(bid - 4096) * 2048; }
    else if (bid < 7168) { s = s2; d = d2; off = (size_t)(bid - 6144) * 2048; }
    else if (bid < 7184) { s = s3; d = d3; off = (size_t)(bid - 7168) * 2048; }
    else if (bid < 7200) { s = s4; d = d4; off = (size_t)(bid - 7184) * 2048; }
    else                 { s = s5; d = d5; off = (size_t)(bid - 7200) * 2048; }
    size_t i = off + (size_t)threadIdx.x * 8;
    float4 a = *(const float4*)&s[i];
    float4 b = *(const float4*)&s[i + 4];
    u16x8 o;
    o[0] = f2bf(a.x); o[1] = f2bf(a.y); o[2] = f2bf(a.z); o[3] = f2bf(a.w);
    o[4] = f2bf(b.x); o[5] = f2bf(b.y); o[6] = f2bf(b.z); o[7] = f2bf(b.w);
    *(u16x8*)&d[i] = o;
}

#define GL_LDS(gp, lp)                                                        \
    __builtin_amdgcn_global_load_lds(                                         \
        (const __attribute__((address_space(1))) void*)(gp),                  \
        (__attribute__((address_space(3))) void*)(lp), 16, 0, 0)
#define BAR() __builtin_amdgcn_s_barrier()
#define LGKM0()                                                               \
    do {                                                                      \
        asm volatile("s_waitcnt lgkmcnt(0)" ::: "memory");                    \
        __builtin_amdgcn_sched_barrier(0);                                    \
    } while (0)
#define VMC4() asm volatile("s_waitcnt vmcnt(4)" ::: "memory")

// ---------------------------------------------------------------------------
// 256x256 GEMM (C = A @ B^T), m201-style 4-phase schedule per K-tile (BK=64).
// LDS: sA/sB[buf][half][128*64] (half = 128 rows), 128 KiB total, dbuf.
// 8 waves (2M x 4N); per-wave C 128x64 = 8x4 16x16x32 frags; wave wm reads
// only A-half wm, wave wn reads only B-half wn>>1.
// Swizzle: LDS[row][slot] holds global k-slot g where slot = g ^ (row&7)
// (g = 8-elem k-block, 8 per 64-k tile). Frag reads: 2 lanes/bank = free.
// Staging is linear (gload_lds) with pre-swizzled source col
// gslot = (l&7)^((l>>3)&7); wave w covers rows {w*8, 64+w*8} of each half.
// Phases = C-quadrants; per phase: ds_reads + stage ONE half-tile ->
// s_barrier -> lgkmcnt(0) -> setprio(1) 16 MFMA setprio(0) -> s_barrier.
// Staging train (staggered, WAR-safe by the phase barriers):
//   ph1: A0(t+1)  ph2: A1(t+1)  ph3: B0(t+2)  ph4: B1(t+2)
// One vmcnt(4) per tile at ph4 end: drains A(t+1) (and B(t+1) from t-1),
// leaves B(t+2) in flight. Never vmcnt(0) in the loop.
// Single frag set per quadrant (af[4][2] + bf01/bf23) -> no reg ping-pong.
// ---------------------------------------------------------------------------
template <int OUT_BF16>
__global__ __launch_bounds__(512, 2) void gemm_bt_256(
    const u16* __restrict__ A, const u16* __restrict__ B,
    void* __restrict__ Cout, int N, int K) {
    __shared__ u16 sA[2][2][128 * 64];
    __shared__ u16 sB[2][2][128 * 64];
    const int tid = threadIdx.x;
    const int lane = tid & 63;
    const int wave = tid >> 6;   // 0..7
    const int wm = wave >> 2;    // 0..1
    const int wn = wave & 3;     // 0..3
    const int bm = blockIdx.y * 256;
    const int bn = blockIdx.x * 256;

    // ---- staging addresses ----
    const int gslot = (lane & 7) ^ ((lane >> 3) & 7);  // pre-swizzled k-slot
    const int srowoff = lane >> 3;                     // 0..7
    const u16* aG = A + (size_t)(bm + wave * 8 + srowoff) * K + gslot * 8;
    const u16* bG = B + (size_t)(bn + wave * 8 + srowoff) * K + gslot * 8;
    const size_t row64 = (size_t)64 * K;    // +64 rows (c=1)
    const size_t row128 = (size_t)128 * K;  // +half

#define STAGE_A(buf, h, kt)                                                   \
    do {                                                                      \
        const u16* g_ = aG + (h) * row128 + (size_t)(kt) * 64;                \
        GL_LDS(g_,         &sA[buf][h][wave * 512]);                          \
        GL_LDS(g_ + row64, &sA[buf][h][(8 + wave) * 512]);                    \
    } while (0)
#define STAGE_B(buf, h, kt)                                                   \
    do {                                                                      \
        const u16* g_ = bG + (h) * row128 + (size_t)(kt) * 64;                \
        GL_LDS(g_,         &sB[buf][h][wave * 512]);                          \
        GL_LDS(g_ + row64, &sB[buf][h][(8 + wave) * 512]);                    \
    } while (0)

    // ---- fragment read bases (elem offsets within a [128][64] half) ----
    const int fr = lane & 15;
    const int kq = lane >> 4;                 // k-block within 32-k step
    const int st0 = kq ^ (fr & 7);            // stored slot, kh2=0
    const int st1 = (4 + kq) ^ (fr & 7);      // stored slot, kh2=1
    const int aB0 = fr * 64 + st0 * 8;
    const int aB1 = fr * 64 + st1 * 8;
    const int bRow = (wn & 1) * 64 + fr;
    const int bB0 = bRow * 64 + st0 * 8;
    const int bB1 = bRow * 64 + st1 * 8;

    floatx4 acc[8][4];
#pragma unroll
    for (int i = 0; i < 8; ++i)
#pragma unroll
        for (int j = 0; j < 4; ++j) acc[i][j] = (floatx4){0.f, 0.f, 0.f, 0.f};

    short8 af[4][2], bf01[2][2], bf23[2][2];

#define MFMA_PH(mibase, BF, nibase)                                           \
    do {                                                                      \
        _Pragma("unroll")                                                     \
        for (int kh = 0; kh < 2; ++kh)                                        \
            _Pragma("unroll")                                                 \
            for (int mi = 0; mi < 4; ++mi)                                    \
                _Pragma("unroll")                                             \
                for (int ni = 0; ni < 2; ++ni)                                \
                    acc[(mibase) + mi][(nibase) + ni] =                       \
                        __builtin_amdgcn_mfma_f32_16x16x32_bf16(              \
                            af[mi][kh], BF[ni][kh],                           \
                            acc[(mibase) + mi][(nibase) + ni], 0, 0, 0);      \
    } while (0)

    // ---- prologue: A(0), B(0), B(1); wait so A(0),B(0) landed ----
    STAGE_A(0, 0, 0);
    STAGE_A(0, 1, 0);
    STAGE_B(0, 0, 0);
    STAGE_B(0, 1, 0);
    STAGE_B(1, 0, 1);
    STAGE_B(1, 1, 1);
    VMC4();
    BAR();

    const int NT = K >> 6;  // power of two (16 or 32)
    for (int t = 0; t < NT; ++t) {
        const int cur = t & 1;
        const int nxt = cur ^ 1;
        const int kA = (t + 1) & (NT - 1);
        const int kB = (t + 2) & (NT - 1);
        const u16* aC = &sA[cur][wm][0];
        const u16* bC = &sB[cur][wn >> 1][0];

        // ---- phase 1: quadrant (mi0-3, ni0-1); stage A0(t+1) ----
#pragma unroll
        for (int mi = 0; mi < 4; ++mi) {
            af[mi][0] = *(const short8*)(aC + aB0 + mi * 16 * 64);
            af[mi][1] = *(const short8*)(aC + aB1 + mi * 16 * 64);
        }
#pragma unroll
        for (int ni = 0; ni < 2; ++ni) {
            bf01[ni][0] = *(const short8*)(bC + bB0 + ni * 16 * 64);
            bf01[ni][1] = *(const short8*)(bC + bB1 + ni * 16 * 64);
        }
        STAGE_A(nxt, 0, kA);
        BAR();
        LGKM0();
        __builtin_amdgcn_s_setprio(1);
        MFMA_PH(0, bf01, 0);
        __builtin_amdgcn_s_setprio(0);
        BAR();

        // ---- phase 2: quadrant (mi0-3, ni2-3); stage A1(t+1) ----
#pragma unroll
        for (int ni = 0; ni < 2; ++ni) {
            bf23[ni][0] = *(const short8*)(bC + bB0 + (32 + ni * 16) * 64);
            bf23[ni][1] = *(const short8*)(bC + bB1 + (32 + ni * 16) * 64);
        }
        STAGE_A(nxt, 1, kA);
        BAR();
        LGKM0();
        __builtin_amdgcn_s_setprio(1);
        MFMA_PH(0, bf23, 2);
        __builtin_amdgcn_s_setprio(0);
        BAR();

        // ---- phase 3: quadrant (mi4-7, ni0-1); stage B0(t+2) ----
#pragma unroll
        for (int mi = 0; mi < 4; ++mi) {
            af[mi][0] = *(const short8*)(aC + aB0 + (64 + mi * 16) * 64);
            af[mi][1] = *(const short8*)(aC + aB1 + (64 + mi * 16) * 64);
        }
        STAGE_B(cur, 0, kB);
        BAR();
        LGKM0();
        __builtin_amdgcn_s_setprio(1);
        MFMA_PH(4, bf01, 0);
        __builtin_amdgcn_s_setprio(0);
        BAR();

        // ---- phase 4: quadrant (mi4-7, ni2-3); stage B1(t+2) ----
        STAGE_B(cur, 1, kB);
        BAR();
        __builtin_amdgcn_s_setprio(1);
        MFMA_PH(4, bf23, 2);
        __builtin_amdgcn_s_setprio(0);
        VMC4();   // A(t+1) + B(t+1) landed; B(t+2) stays in flight
        BAR();
    }

    // epilogue: C/D 16x16 layout: col = lane&15, row = (lane>>4)*4 + r
    const int cc = lane & 15;
    const int rb = (lane >> 4) * 4;
#pragma unroll
    for (int mi = 0; mi < 8; ++mi)
#pragma unroll
        for (int ni = 0; ni < 4; ++ni)
#pragma unroll
            for (int r = 0; r < 4; ++r) {
                int grow = bm + wm * 128 + mi * 16 + rb + r;
                int gcol = bn + wn * 64 + ni * 16 + cc;
                float v = acc[mi][ni][r];
                if (OUT_BF16)
                    ((u16*)Cout)[(size_t)grow * N + gcol] = f2bf(v);
                else
                    ((float*)Cout)[(size_t)grow * N + gcol] = v;
            }
#undef STAGE_A
#undef STAGE_B
#undef MFMA_PH
}

// C[m][n] = sum_k A[m,k]*B[n,k]; A: MxK bf16, B: NxK bf16, row-major.
// 128x128 tile, BK=32, 4 waves (2x2), each wave 64x64 via 2x2 of 32x32x16 MFMA
// (2 K-steps per BK). Kept for the thin out-proj GEMM (N=1024: 512 blocks).
template <int OUT_BF16>
__global__ __launch_bounds__(256) void gemm_bt_mfma(
    const u16* __restrict__ A, const u16* __restrict__ B,
    void* __restrict__ Cout, int N, int K) {
    __shared__ u16 As[128 * 32];
    __shared__ u16 Bs[128 * 32];
    const int tid = threadIdx.x;
    const int lane = tid & 63;
    const int wave = tid >> 6;
    const int bm = blockIdx.y * 128;
    const int bn = blockIdx.x * 128;

    const int kbg = (lane & 3) ^ ((lane >> 3) & 3);
    const int srow = lane >> 2;
    const u16* ag[2];
    const u16* bg[2];
#pragma unroll
    for (int p = 0; p < 2; ++p) {
        int c = wave * 2 + p;
        ag[p] = A + (size_t)(bm + c * 16 + srow) * K + kbg * 8;
        bg[p] = B + (size_t)(bn + c * 16 + srow) * K + kbg * 8;
    }
    const int frow = lane & 31;
    const int khi = lane >> 5;
    const int wr = (wave >> 1) * 64;
    const int wc = (wave & 1) * 64;
    int aoff[2][2], boff[2][2];
#pragma unroll
    for (int mi = 0; mi < 2; ++mi)
#pragma unroll
        for (int kh = 0; kh < 2; ++kh) {
            int rA = wr + mi * 32 + frow;
            int rB = wc + mi * 32 + frow;
            int kb = kh * 2 + khi;
            aoff[mi][kh] = rA * 32 + (kb ^ ((rA >> 1) & 3)) * 8;
            boff[mi][kh] = rB * 32 + (kb ^ ((rB >> 1) & 3)) * 8;
        }
    floatx16 acc[2][2];
#pragma unroll
    for (int i = 0; i < 2; ++i)
#pragma unroll
        for (int j = 0; j < 2; ++j) acc[i][j] = (floatx16)(0.f);

    for (int k0 = 0; k0 < K; k0 += 32) {
        __syncthreads();
#pragma unroll
        for (int p = 0; p < 2; ++p) {
            int c = wave * 2 + p;
            __builtin_amdgcn_global_load_lds(
                (const __attribute__((address_space(1))) void*)ag[p],
                (__attribute__((address_space(3))) void*)&As[c * 512], 16, 0, 0);
            __builtin_amdgcn_global_load_lds(
                (const __attribute__((address_space(1))) void*)bg[p],
                (__attribute__((address_space(3))) void*)&Bs[c * 512], 16, 0, 0);
            ag[p] += 32;
            bg[p] += 32;
        }
        __syncthreads();
        short8 af[2][2], bf[2][2];
#pragma unroll
        for (int mi = 0; mi < 2; ++mi)
#pragma unroll
            for (int kh = 0; kh < 2; ++kh) {
                af[mi][kh] = *(const short8*)&As[aoff[mi][kh]];
                bf[mi][kh] = *(const short8*)&Bs[boff[mi][kh]];
            }
#pragma unroll
        for (int kh = 0; kh < 2; ++kh)
#pragma unroll
            for (int mi = 0; mi < 2; ++mi)
#pragma unroll
                for (int ni = 0; ni < 2; ++ni)
                    acc[mi][ni] = __builtin_amdgcn_mfma_f32_32x32x16_bf16(
                        af[mi][kh], bf[ni][kh], acc[mi][ni], 0, 0, 0);
    }
    // C/D layout (m74/m101): col = lane&31, row = (reg&3) + 8*(reg>>2) + 4*(lane>>5)
    const int cc = lane & 31;
    const int rbase = 4 * (lane >> 5);
#pragma unroll
    for (int mi = 0; mi < 2; ++mi)
#pragma unroll
        for (int ni = 0; ni < 2; ++ni)
#pragma unroll
            for (int r = 0; r < 16; ++r) {
                int grow = bm + wr + mi * 32 + (r & 3) + 8 * (r >> 2) + rbase;
                int gcol = bn + wc + ni * 32 + cc;
                float v = acc[mi][ni][r];
                if (OUT_BF16)
                    ((u16*)Cout)[(size_t)grow * N + gcol] = f2bf(v);
                else
                    ((float*)Cout)[(size_t)grow * N + gcol] = v;
            }
}

// depthwise causal conv (DC=4) + bias + silu + row-mean.
__global__ __launch_bounds__(256) void conv_silu_avg(
    const u16* __restrict__ xin, const float* __restrict__ cw,
    const float* __restrict__ cb, u16* __restrict__ xconv,
    float* __restrict__ xavg) {
    const int blk = blockIdx.x;        // 512 blocks
    const int b = blk >> 7;
    const int lc = blk & 127;
    const int row0 = b * LL + lc * 16;
    const int tid = threadIdx.x;
    const int lane = tid & 63, wave = tid >> 6;
    const int d0 = tid * 8;
    float4 cwv[8];
    float cbv[8];
#pragma unroll
    for (int e = 0; e < 8; ++e) cwv[e] = *(const float4*)&cw[(d0 + e) * 4];
#pragma unroll
    for (int e = 0; e < 8; e += 4) {
        float4 c = *(const float4*)&cb[d0 + e];
        cbv[e] = c.x; cbv[e + 1] = c.y; cbv[e + 2] = c.z; cbv[e + 3] = c.w;
    }
    u16x8 w0, w1, w2;
    if (lc == 0) {
        w0 = (u16x8)0; w1 = (u16x8)0; w2 = (u16x8)0;
    } else {
        w0 = *(const u16x8*)&xin[(size_t)(row0 - 3) * (2 * DINNER) + d0];
        w1 = *(const u16x8*)&xin[(size_t)(row0 - 2) * (2 * DINNER) + d0];
        w2 = *(const u16x8*)&xin[(size_t)(row0 - 1) * (2 * DINNER) + d0];
    }
    float sums[16];
#pragma unroll
    for (int t = 0; t < 16; ++t) {
        u16x8 cur = *(const u16x8*)&xin[(size_t)(row0 + t) * (2 * DINNER) + d0];
        float lsum = 0.f;
        u16x8 o;
#pragma unroll
        for (int e = 0; e < 8; ++e) {
            float acc = cbv[e];
            acc += bf2f(w0[e]) * cwv[e].x;
            acc += bf2f(w1[e]) * cwv[e].y;
            acc += bf2f(w2[e]) * cwv[e].z;
            acc += bf2f(cur[e]) * cwv[e].w;
            float s = silu_f(acc);
            lsum += s;
            o[e] = f2bf(s);
        }
        *(u16x8*)&xconv[(size_t)(row0 + t) * DINNER + d0] = o;
        sums[t] = lsum;
        w0 = w1; w1 = w2; w2 = cur;
    }
#pragma unroll
    for (int off = 32; off; off >>= 1)
#pragma unroll
        for (int t = 0; t < 16; ++t) sums[t] += __shfl_down(sums[t], off);
    __shared__ float wred[4][16];
    if (lane == 0) {
#pragma unroll
        for (int t = 0; t < 16; ++t) wred[wave][t] = sums[t];
    }
    __syncthreads();
    if (tid < 16)
        xavg[row0 + tid] = (wred[0][tid] + wred[1][tid] + wred[2][tid] + wred[3][tid]) *
                           (1.f / DINNER);
}

// delta/B/C projections: thin GEMM (8192 x 48 x 2048), K split across waves.
// 256 blocks x 32 rows; each wave owns a K-quarter (512), frags loaded
// directly from global (L2/LLC-resident), cross-wave reduce via LDS.
__global__ __launch_bounds__(256) void dbc_direct(
    const u16* __restrict__ xconv, const u16* __restrict__ wcat,
    const float* __restrict__ db, const float* __restrict__ A_log,
    const float* __restrict__ xavg,
    float* __restrict__ a_out, float* __restrict__ u_out, float* __restrict__ c_out) {
    __shared__ float part[4][32][48];
    const int tid = threadIdx.x;
    const int lane = tid & 63;
    const int wave = tid >> 6;
    const int bm = blockIdx.x * 32;
    const int fr = lane & 15;
    const int kq = lane >> 4;
    const int k0 = wave * 512 + kq * 8;

    const u16* ap0 = xconv + (size_t)(bm + fr) * DINNER + k0;
    const u16* ap1 = xconv + (size_t)(bm + 16 + fr) * DINNER + k0;
    const u16* bp0 = wcat + (size_t)(fr) * DINNER + k0;
    const u16* bp1 = wcat + (size_t)(16 + fr) * DINNER + k0;
    const u16* bp2 = wcat + (size_t)(32 + fr) * DINNER + k0;

    floatx4 acc[2][3];
#pragma unroll
    for (int mi = 0; mi < 2; ++mi)
#pragma unroll
        for (int ni = 0; ni < 3; ++ni) acc[mi][ni] = (floatx4){0.f, 0.f, 0.f, 0.f};

#pragma unroll 4
    for (int kk = 0; kk < 16; ++kk) {
        short8 a0 = *(const short8*)ap0;
        short8 a1 = *(const short8*)ap1;
        short8 b0 = *(const short8*)bp0;
        short8 b1 = *(const short8*)bp1;
        short8 b2 = *(const short8*)bp2;
        ap0 += 32; ap1 += 32; bp0 += 32; bp1 += 32; bp2 += 32;
        acc[0][0] = __builtin_amdgcn_mfma_f32_16x16x32_bf16(a0, b0, acc[0][0], 0, 0, 0);
        acc[0][1] = __builtin_amdgcn_mfma_f32_16x16x32_bf16(a0, b1, acc[0][1], 0, 0, 0);
        acc[0][2] = __builtin_amdgcn_mfma_f32_16x16x32_bf16(a0, b2, acc[0][2], 0, 0, 0);
        acc[1][0] = __builtin_amdgcn_mfma_f32_16x16x32_bf16(a1, b0, acc[1][0], 0, 0, 0);
        acc[1][1] = __builtin_amdgcn_mfma_f32_16x16x32_bf16(a1, b1, acc[1][1], 0, 0, 0);
        acc[1][2] = __builtin_amdgcn_mfma_f32_16x16x32_bf16(a1, b2, acc[1][2], 0, 0, 0);
    }
    // C/D 16x16 layout: col = lane&15, row = (lane>>4)*4 + r
    const int cr = kq * 4;
#pragma unroll
    for (int mi = 0; mi < 2; ++mi)
#pragma unroll
        for (int ni = 0; ni < 3; ++ni)
#pragma unroll
            for (int r = 0; r < 4; ++r)
                part[wave][mi * 16 + cr + r][ni * 16 + fr] = acc[mi][ni][r];
    __syncthreads();
#pragma unroll
    for (int it = tid; it < 512; it += 256) {
        int row = it >> 4;
        int s = it & 15;
        float sd = 0.f, sb = 0.f, sc = 0.f;
#pragma unroll
        for (int w = 0; w < 4; ++w) {
            sd += part[w][row][s];
            sb += part[w][row][s + 16];
            sc += part[w][row][s + 32];
        }
        int grow = bm + row;
        float Aa = -__expf(A_log[s]);
        float pre = sd + db[s];
        float delta = (pre > 20.f) ? pre : log1pf(__expf(pre));
        a_out[grow * NSTATE + s] = __expf(delta * Aa);
        u_out[grow * NSTATE + s] = delta * sb * xavg[grow];
        c_out[grow * NSTATE + s] = sc;
    }
}

// ---- parallel linear scan, 3 phases ----
__global__ __launch_bounds__(256) void scan_p1(
    const float* __restrict__ a, const float* __restrict__ u,
    float* __restrict__ Pc, float* __restrict__ H0c) {
    int gid = blockIdx.x * 256 + threadIdx.x;
    int s = gid & 15, seg = (gid >> 4) & (NSEG - 1), b = gid >> 10;
    size_t base = (size_t)(b * LL + seg * SEGLEN) * NSTATE + s;
    float P = 1.f, h = 0.f;
#pragma unroll 8
    for (int t = 0; t < SEGLEN; ++t) {
        float av = a[base + (size_t)t * NSTATE];
        float uv = u[base + (size_t)t * NSTATE];
        h = fmaf(av, h, uv);
        P *= av;
    }
    int o = (b * NSEG + seg) * NSTATE + s;
    Pc[o] = P;
    H0c[o] = h;
}

__global__ __launch_bounds__(64) void scan_p2(
    const float* __restrict__ Pc, const float* __restrict__ H0c,
    float* __restrict__ hstart) {
    int lane = threadIdx.x;
    int b = lane >> 4, s = lane & 15;
    float h = 0.f;
#pragma unroll 8
    for (int seg = 0; seg < NSEG; ++seg) {
        int o = (b * NSEG + seg) * NSTATE + s;
        hstart[o] = h;
        h = fmaf(Pc[o], h, H0c[o]);
    }
}

__global__ __launch_bounds__(256) void scan_p3(
    const float* __restrict__ a, const float* __restrict__ u,
    const float* __restrict__ c, const float* __restrict__ hstart,
    float* __restrict__ y) {
    int gid = blockIdx.x * 256 + threadIdx.x;
    int s = gid & 15, seg = (gid >> 4) & (NSEG - 1), b = gid >> 10;
    float h = hstart[(b * NSEG + seg) * NSTATE + s];
    size_t base = (size_t)(b * LL + seg * SEGLEN) * NSTATE + s;
#pragma unroll 8
    for (int t = 0; t < SEGLEN; ++t) {
        float av = a[base + (size_t)t * NSTATE];
        float uv = u[base + (size_t)t * NSTATE];
        float cv = c[base + (size_t)t * NSTATE];
        h = fmaf(av, h, uv);
        float p = h * cv;
        p += __shfl_xor(p, 1);
        p += __shfl_xor(p, 2);
        p += __shfl_xor(p, 4);
        p += __shfl_xor(p, 8);
        if (s == 0) y[b * LL + seg * SEGLEN + t] = p;
    }
}

// y_skip = y*silu(x_gate) + x_conv*D  -> bf16
__global__ __launch_bounds__(256) void gate_skip(
    const u16* __restrict__ xin, const float* __restrict__ y,
    const float* __restrict__ Dv, const u16* __restrict__ xconv,
    u16* __restrict__ yskip) {
    size_t i = ((size_t)blockIdx.x * 256 + threadIdx.x) * 8;
    int row = (int)(i >> 11);
    int d = (int)(i & (DINNER - 1));
    u16x8 g = *(const u16x8*)&xin[(size_t)row * (2 * DINNER) + DINNER + d];
    u16x8 xc = *(const u16x8*)&xconv[i];
    float yv = y[row];
    u16x8 o;
#pragma unroll
    for (int e = 0; e < 8; ++e) {
        float gv = silu_f(bf2f(g[e]));
        float v = yv * gv + bf2f(xc[e]) * Dv[d + e];
        o[e] = f2bf(v);
    }
    *(u16x8*)&yskip[i] = o;
}

extern "C" void kernel_launch(void* const* d_in, const int* in_sizes, int n_in,
                              void* d_out, int out_size, void* d_ws, size_t ws_size,
                              hipStream_t stream) {
    const float* x       = (const float*)d_in[0];
    const float* w_in    = (const float*)d_in[1];
    const float* conv_w  = (const float*)d_in[2];
    const float* conv_b  = (const float*)d_in[3];
    const float* A_log   = (const float*)d_in[4];
    const float* Dv      = (const float*)d_in[5];
    const float* delta_w = (const float*)d_in[6];
    const float* delta_b = (const float*)d_in[7];
    const float* B_w     = (const float*)d_in[8];
    const float* C_w     = (const float*)d_in[9];
    const float* out_w   = (const float*)d_in[10];
    float* out = (float*)d_out;

    u16* xb  = (u16*)d_ws;                 // 8192*1024
    u16* wb  = xb + 8388608;               // 4096*1024
    u16* owb = wb + 4194304;               // 1024*2048
    u16* wsb = owb + 2097152;              // 48*2048 (concat dw,bw,cw)
    u16* xin = wsb + 98304;                // 8192*4096
    u16* xcv = xin + 33554432;             // 8192*2048
    u16* ysk = xcv + 16777216;             // 8192*2048
    float* fb     = (float*)(ysk + 16777216);
    float* abuf   = fb;                    // 8192*16
    float* ubuf   = abuf + 131072;
    float* cbuf   = ubuf + 131072;
    float* pbuf   = cbuf + 131072;         // 4*64*16
    float* h0buf  = pbuf + 4096;
    float* hsbuf  = h0buf + 4096;
    float* ybuf   = hsbuf + 4096;          // 8192
    float* avgbuf = ybuf + 8192;           // 8192

    cvt_multi<<<7216, 256, 0, stream>>>(x, w_in, out_w, delta_w, B_w, C_w,
                                        xb, wb, owb, wsb, wsb + 32768, wsb + 65536);

    // x_inner = x @ in_proj_w.T : (8192x1024)@(4096x1024)^T -> bf16
    gemm_bt_256<1><<<dim3(16, 32), 512, 0, stream>>>(xb, wb, xin, 2 * DINNER, DMODEL);

    conv_silu_avg<<<512, 256, 0, stream>>>(xin, conv_w, conv_b, xcv, avgbuf);
    dbc_direct<<<256, 256, 0, stream>>>(xcv, wsb, delta_b, A_log, avgbuf,
                                        abuf, ubuf, cbuf);

    scan_p1<<<16, 256, 0, stream>>>(abuf, ubuf, pbuf, h0buf);
    scan_p2<<<1, 64, 0, stream>>>(pbuf, h0buf, hsbuf);
    scan_p3<<<16, 256, 0, stream>>>(abuf, ubuf, cbuf, hsbuf, ybuf);

    gate_skip<<<NROW * DINNER / 8 / 256, 256, 0, stream>>>(xin, ybuf, Dv, xcv, ysk);

    // out = y_skip @ out_proj_w.T : (8192x2048)@(1024x2048)^T -> fp32
    gemm_bt_mfma<0><<<dim3(8, 64), 256, 0, stream>>>(ysk, owb, out, DMODEL, DINNER);
}

// Round 4
// 302.128 us; speedup vs baseline: 1.1364x; 1.0503x over previous
//
#include <hip/hip_runtime.h>
#include <cmath>

#define LL 2048
#define NROW 8192
#define DMODEL 1024
#define DINNER 2048
#define NSTATE 16
#define NSEG 64
#define SEGLEN 32   // NSEG * SEGLEN == LL

typedef unsigned short u16;
typedef __attribute__((ext_vector_type(8))) unsigned short u16x8;
typedef __attribute__((ext_vector_type(8))) short short8;
typedef __attribute__((ext_vector_type(4))) float floatx4;
typedef __attribute__((ext_vector_type(16))) float floatx16;

__device__ __forceinline__ float bf2f(u16 h) {
    unsigned u = ((unsigned)h) << 16;
    float f;
    __builtin_memcpy(&f, &u, 4);
    return f;
}
__device__ __forceinline__ u16 f2bf(float f) {
    unsigned u;
    __builtin_memcpy(&u, &f, 4);
    u = u + 0x7fffu + ((u >> 16) & 1u);
    return (u16)(u >> 16);
}
__device__ __forceinline__ float silu_f(float x) { return x / (1.f + __expf(-x)); }

// One kernel converts all six fp32->bf16 tensors (2048 elems per block).
__global__ __launch_bounds__(256) void cvt_multi(
    const float* __restrict__ s0, const float* __restrict__ s1,
    const float* __restrict__ s2, const float* __restrict__ s3,
    const float* __restrict__ s4, const float* __restrict__ s5,
    u16* __restrict__ d0, u16* __restrict__ d1, u16* __restrict__ d2,
    u16* __restrict__ d3, u16* __restrict__ d4, u16* __restrict__ d5) {
    int bid = blockIdx.x;
    const float* s;
    u16* d;
    size_t off;
    if (bid < 4096)      { s = s0; d = d0; off = (size_t)bid * 2048; }
    else if (bid < 6144) { s = s1; d = d1; off = (size_t)(bid - 4096) * 2048; }
    else if (bid < 7168) { s = s2; d = d2; off = (size_t)(bid - 6144) * 2048; }
    else if (bid < 7184) { s = s3; d = d3; off = (size_t)(bid - 7168) * 2048; }
    else if (bid < 7200) { s = s4; d = d4; off = (size_t)(bid - 7184) * 2048; }
    else                 { s = s5; d = d5; off = (size_t)(bid - 7200) * 2048; }
    size_t i = off + (size_t)threadIdx.x * 8;
    float4 a = *(const float4*)&s[i];
    float4 b = *(const float4*)&s[i + 4];
    u16x8 o;
    o[0] = f2bf(a.x); o[1] = f2bf(a.y); o[2] = f2bf(a.z); o[3] = f2bf(a.w);
    o[4] = f2bf(b.x); o[5] = f2bf(b.y); o[6] = f2bf(b.z); o[7] = f2bf(b.w);
    *(u16x8*)&d[i] = o;
}

#define GL_LDS(gp, lp)                                                        \
    __builtin_amdgcn_global_load_lds(                                         \
        (const __attribute__((address_space(1))) void*)(gp),                  \
        (__attribute__((address_space(3))) void*)(lp), 16, 0, 0)
#define BAR() __builtin_amdgcn_s_barrier()
#define SB0() __builtin_amdgcn_sched_barrier(0)
#define LGKM0()                                                               \
    do {                                                                      \
        asm volatile("s_waitcnt lgkmcnt(0)" ::: "memory");                    \
        __builtin_amdgcn_sched_barrier(0);                                    \
    } while (0)
#define VMC4() asm volatile("s_waitcnt vmcnt(4)" ::: "memory")
#define PRIO1() __builtin_amdgcn_s_setprio(1)
#define PRIO0() __builtin_amdgcn_s_setprio(0)

// ---------------------------------------------------------------------------
// 256x256 GEMM (C = A @ B^T), reads-after-MFMA pipelined 4-phase schedule.
// Per phase: lgkm(0) -> MFMA x16 -> issue NEXT phase's ds_reads + 1 stage.
// LDS read service hides under the matrix pipe drain (depth-1 pipeline).
// 2 barriers/tile (mid + end), each preceded by counted vmcnt(4):
//   mid  (after ph2): B(t+1) landed  (ph3 reads bf01' from nxt buf)
//   end  (after ph4): A(t+1) landed  (afX' read right after, for ph1)
// Staging train: A(t+1) at ph1/ph2, B(t+2) at ph3/ph4 -> 4 loads in flight
// at each vmcnt(4); never vmcnt(0) in the loop.
// Frag regs: afX/afY (two A-sets) + bf01/bf23 (B reused ph1+ph3 / ph2+ph4)
// = 96 VGPR + 128 acc. Loop unrolled x2 so buffer parity is compile-time.
// Staging pointers run up to 2 tiles past K-end -> lands in the adjacent
// workspace buffer (valid memory, written to a dead LDS buffer). Callers
// must guarantee the allocation after A and B is readable (true here:
// xb->wb, wb->owb).
// LDS swizzle: [128][64]-elem half-tiles, stored slot = g ^ (row&7); frag
// reads 8 lanes/slot-group spread over all 32 banks (0 conflicts, R1/R3).
// XCD-aware bijective block swizzle (512 blocks % 8 == 0).
// ---------------------------------------------------------------------------
template <int OUT_BF16>
__global__ __launch_bounds__(512, 2) void gemm_bt_256(
    const u16* __restrict__ A, const u16* __restrict__ B,
    void* __restrict__ Cout, int N, int K) {
    __shared__ u16 sAf[2 * 2 * 128 * 64];   // [buf][half][row*64 + slot*8]
    __shared__ u16 sBf[2 * 2 * 128 * 64];
    const int tid = threadIdx.x;
    const int lane = tid & 63;
    const int wave = tid >> 6;   // 0..7
    const int wm = wave >> 2;    // 0..1
    const int wn = wave & 3;     // 0..3

    // XCD swizzle: grid is (N/256) x (M/256); linearize, chunk per XCD.
    const int gx = gridDim.x;
    const int nwg = gx * gridDim.y;
    const int cpx = nwg >> 3;                       // nwg % 8 == 0 here
    int lin = blockIdx.y * gx + blockIdx.x;
    int swz = (lin & 7) * cpx + (lin >> 3);
    const int bm = (swz / gx) * 256;
    const int bn = (swz % gx) * 256;

    // ---- staging addresses (pre-swizzled source k-slot) ----
    const int gslot = (lane & 7) ^ ((lane >> 3) & 7);
    const int srowoff = lane >> 3;                  // 0..7
    const u16* aStage = A + (size_t)(bm + wave * 8 + srowoff) * K + gslot * 8 + 64;
    const u16* bStage = B + (size_t)(bn + wave * 8 + srowoff) * K + gslot * 8 + 128;
    const size_t row64 = (size_t)64 * K;
    const size_t row128 = (size_t)128 * K;

#define STAGE_A(BUF, H, PTR)                                                  \
    do {                                                                      \
        GL_LDS((PTR) + (H) * row128,         &sAf[(BUF) * 16384 + (H) * 8192 + wave * 512]); \
        GL_LDS((PTR) + (H) * row128 + row64, &sAf[(BUF) * 16384 + (H) * 8192 + (8 + wave) * 512]); \
    } while (0)
#define STAGE_B(BUF, H, PTR)                                                  \
    do {                                                                      \
        GL_LDS((PTR) + (H) * row128,         &sBf[(BUF) * 16384 + (H) * 8192 + wave * 512]); \
        GL_LDS((PTR) + (H) * row128 + row64, &sBf[(BUF) * 16384 + (H) * 8192 + (8 + wave) * 512]); \
    } while (0)

    // ---- fragment read bases (element offsets) ----
    const int fr = lane & 15;
    const int kq = lane >> 4;
    const int st0 = kq ^ (fr & 7);
    const int st1 = (4 + kq) ^ (fr & 7);
    const int aRd0 = wm * 8192 + fr * 64 + st0 * 8;
    const int aRd1 = wm * 8192 + fr * 64 + st1 * 8;
    const int bRow = (wn & 1) * 64 + fr;
    const int bRd0 = (wn >> 1) * 8192 + bRow * 64 + st0 * 8;
    const int bRd1 = (wn >> 1) * 8192 + bRow * 64 + st1 * 8;

#define RD_A(dst, BUF, R0)                                                    \
    do {                                                                      \
        _Pragma("unroll")                                                     \
        for (int mi = 0; mi < 4; ++mi) {                                      \
            dst[mi][0] = *(const short8*)&sAf[(BUF) * 16384 + aRd0 + ((R0) + mi * 16) * 64]; \
            dst[mi][1] = *(const short8*)&sAf[(BUF) * 16384 + aRd1 + ((R0) + mi * 16) * 64]; \
        }                                                                     \
    } while (0)
#define RD_B(dst, BUF, R0)                                                    \
    do {                                                                      \
        _Pragma("unroll")                                                     \
        for (int ni = 0; ni < 2; ++ni) {                                      \
            dst[ni][0] = *(const short8*)&sBf[(BUF) * 16384 + bRd0 + ((R0) + ni * 16) * 64]; \
            dst[ni][1] = *(const short8*)&sBf[(BUF) * 16384 + bRd1 + ((R0) + ni * 16) * 64]; \
        }                                                                     \
    } while (0)
#define MFMA_PH(AF, RB, BF, CB)                                               \
    do {                                                                      \
        _Pragma("unroll")                                                     \
        for (int kh = 0; kh < 2; ++kh)                                        \
            _Pragma("unroll")                                                 \
            for (int mi = 0; mi < 4; ++mi)                                    \
                _Pragma("unroll")                                             \
                for (int ni = 0; ni < 2; ++ni)                                \
                    acc[(RB) + mi][(CB) + ni] =                               \
                        __builtin_amdgcn_mfma_f32_16x16x32_bf16(              \
                            AF[mi][kh], BF[ni][kh],                           \
                            acc[(RB) + mi][(CB) + ni], 0, 0, 0);              \
    } while (0)

    floatx4 acc[8][4];
#pragma unroll
    for (int i = 0; i < 8; ++i)
#pragma unroll
        for (int j = 0; j < 4; ++j) acc[i][j] = (floatx4){0.f, 0.f, 0.f, 0.f};

    short8 afX[4][2], afY[4][2], bf01[2][2], bf23[2][2];

    // ---- prologue: stage A(0),B(0),B(1); vmcnt(4) leaves B(1) in flight ----
    {
        const u16* a0 = aStage - 64;
        const u16* b0 = bStage - 128;
        STAGE_A(0, 0, a0);
        STAGE_A(0, 1, a0);
        STAGE_B(0, 0, b0);
        STAGE_B(0, 1, b0);
        STAGE_B(1, 0, b0 + 64);
        STAGE_B(1, 1, b0 + 64);
    }
    VMC4();
    BAR();
    RD_A(afX, 0, 0);
    RD_B(bf01, 0, 0);
    SB0();

// TILE body; CUR/NXT compile-time via x2 unroll.
#define TILE(CUR, NXT)                                                        \
    /* ph1: MFMA q0 x n01; then read bf23(cur), stage A0(t+1) */              \
    LGKM0();                                                                  \
    PRIO1();                                                                  \
    MFMA_PH(afX, 0, bf01, 0);                                                 \
    PRIO0();                                                                  \
    SB0();                                                                    \
    RD_B(bf23, CUR, 32);                                                      \
    STAGE_A(NXT, 0, aStage);                                                  \
    SB0();                                                                    \
    /* ph2: MFMA q0 x n23; then read afY(cur), stage A1(t+1); mid sync */     \
    LGKM0();                                                                  \
    PRIO1();                                                                  \
    MFMA_PH(afX, 0, bf23, 2);                                                 \
    PRIO0();                                                                  \
    SB0();                                                                    \
    RD_A(afY, CUR, 64);                                                       \
    STAGE_A(NXT, 1, aStage);                                                  \
    VMC4(); /* B(t+1) landed */                                               \
    BAR();                                                                    \
    /* ph3: MFMA q1 x n01; then read bf01'(nxt), stage B0(t+2) */             \
    LGKM0();                                                                  \
    PRIO1();                                                                  \
    MFMA_PH(afY, 4, bf01, 0);                                                 \
    PRIO0();                                                                  \
    SB0();                                                                    \
    RD_B(bf01, NXT, 0);                                                       \
    STAGE_B(CUR, 0, bStage);                                                  \
    SB0();                                                                    \
    /* ph4: MFMA q1 x n23; stage B1(t+2); end sync; read afX'(nxt) */         \
    PRIO1();                                                                  \
    MFMA_PH(afY, 4, bf23, 2);                                                 \
    PRIO0();                                                                  \
    SB0();                                                                    \
    STAGE_B(CUR, 1, bStage);                                                  \
    VMC4(); /* A(t+1) landed */                                               \
    BAR();                                                                    \
    RD_A(afX, NXT, 0);                                                        \
    SB0();                                                                    \
    aStage += 64;                                                             \
    bStage += 64;

    const int NT = K >> 6;  // even (16 here)
    for (int t = 0; t < NT; t += 2) {
        TILE(0, 1)
        TILE(1, 0)
    }
#undef TILE

    // epilogue: C/D 16x16 layout: col = lane&15, row = (lane>>4)*4 + r
    const int cc = lane & 15;
    const int rb = (lane >> 4) * 4;
#pragma unroll
    for (int mi = 0; mi < 8; ++mi)
#pragma unroll
        for (int ni = 0; ni < 4; ++ni)
#pragma unroll
            for (int r = 0; r < 4; ++r) {
                int grow = bm + wm * 128 + mi * 16 + rb + r;
                int gcol = bn + wn * 64 + ni * 16 + cc;
                float v = acc[mi][ni][r];
                if (OUT_BF16)
                    ((u16*)Cout)[(size_t)grow * N + gcol] = f2bf(v);
                else
                    ((float*)Cout)[(size_t)grow * N + gcol] = v;
            }
#undef STAGE_A
#undef STAGE_B
#undef RD_A
#undef RD_B
#undef MFMA_PH
}

// C[m][n] = sum_k A[m,k]*B[n,k]; A: MxK bf16, B: NxK bf16, row-major.
// 128x128 tile, BK=32, 4 waves (2x2), each wave 64x64 via 2x2 of 32x32x16 MFMA
// (2 K-steps per BK). Kept for the thin out-proj GEMM (N=1024: 512 blocks).
template <int OUT_BF16>
__global__ __launch_bounds__(256) void gemm_bt_mfma(
    const u16* __restrict__ A, const u16* __restrict__ B,
    void* __restrict__ Cout, int N, int K) {
    __shared__ u16 As[128 * 32];
    __shared__ u16 Bs[128 * 32];
    const int tid = threadIdx.x;
    const int lane = tid & 63;
    const int wave = tid >> 6;
    const int bm = blockIdx.y * 128;
    const int bn = blockIdx.x * 128;

    const int kbg = (lane & 3) ^ ((lane >> 3) & 3);
    const int srow = lane >> 2;
    const u16* ag[2];
    const u16* bg[2];
#pragma unroll
    for (int p = 0; p < 2; ++p) {
        int c = wave * 2 + p;
        ag[p] = A + (size_t)(bm + c * 16 + srow) * K + kbg * 8;
        bg[p] = B + (size_t)(bn + c * 16 + srow) * K + kbg * 8;
    }
    const int frow = lane & 31;
    const int khi = lane >> 5;
    const int wr = (wave >> 1) * 64;
    const int wc = (wave & 1) * 64;
    int aoff[2][2], boff[2][2];
#pragma unroll
    for (int mi = 0; mi < 2; ++mi)
#pragma unroll
        for (int kh = 0; kh < 2; ++kh) {
            int rA = wr + mi * 32 + frow;
            int rB = wc + mi * 32 + frow;
            int kb = kh * 2 + khi;
            aoff[mi][kh] = rA * 32 + (kb ^ ((rA >> 1) & 3)) * 8;
            boff[mi][kh] = rB * 32 + (kb ^ ((rB >> 1) & 3)) * 8;
        }
    floatx16 acc[2][2];
#pragma unroll
    for (int i = 0; i < 2; ++i)
#pragma unroll
        for (int j = 0; j < 2; ++j) acc[i][j] = (floatx16)(0.f);

    for (int k0 = 0; k0 < K; k0 += 32) {
        __syncthreads();
#pragma unroll
        for (int p = 0; p < 2; ++p) {
            int c = wave * 2 + p;
            __builtin_amdgcn_global_load_lds(
                (const __attribute__((address_space(1))) void*)ag[p],
                (__attribute__((address_space(3))) void*)&As[c * 512], 16, 0, 0);
            __builtin_amdgcn_global_load_lds(
                (const __attribute__((address_space(1))) void*)bg[p],
                (__attribute__((address_space(3))) void*)&Bs[c * 512], 16, 0, 0);
            ag[p] += 32;
            bg[p] += 32;
        }
        __syncthreads();
        short8 af[2][2], bf[2][2];
#pragma unroll
        for (int mi = 0; mi < 2; ++mi)
#pragma unroll
            for (int kh = 0; kh < 2; ++kh) {
                af[mi][kh] = *(const short8*)&As[aoff[mi][kh]];
                bf[mi][kh] = *(const short8*)&Bs[boff[mi][kh]];
            }
#pragma unroll
        for (int kh = 0; kh < 2; ++kh)
#pragma unroll
            for (int mi = 0; mi < 2; ++mi)
#pragma unroll
                for (int ni = 0; ni < 2; ++ni)
                    acc[mi][ni] = __builtin_amdgcn_mfma_f32_32x32x16_bf16(
                        af[mi][kh], bf[ni][kh], acc[mi][ni], 0, 0, 0);
    }
    // C/D layout (m74/m101): col = lane&31, row = (reg&3) + 8*(reg>>2) + 4*(lane>>5)
    const int cc = lane & 31;
    const int rbase = 4 * (lane >> 5);
#pragma unroll
    for (int mi = 0; mi < 2; ++mi)
#pragma unroll
        for (int ni = 0; ni < 2; ++ni)
#pragma unroll
            for (int r = 0; r < 16; ++r) {
                int grow = bm + wr + mi * 32 + (r & 3) + 8 * (r >> 2) + rbase;
                int gcol = bn + wc + ni * 32 + cc;
                float v = acc[mi][ni][r];
                if (OUT_BF16)
                    ((u16*)Cout)[(size_t)grow * N + gcol] = f2bf(v);
                else
                    ((float*)Cout)[(size_t)grow * N + gcol] = v;
            }
}

// depthwise causal conv (DC=4) + bias + silu + row-mean.
__global__ __launch_bounds__(256) void conv_silu_avg(
    const u16* __restrict__ xin, const float* __restrict__ cw,
    const float* __restrict__ cb, u16* __restrict__ xconv,
    float* __restrict__ xavg) {
    const int blk = blockIdx.x;        // 512 blocks
    const int b = blk >> 7;
    const int lc = blk & 127;
    const int row0 = b * LL + lc * 16;
    const int tid = threadIdx.x;
    const int lane = tid & 63, wave = tid >> 6;
    const int d0 = tid * 8;
    float4 cwv[8];
    float cbv[8];
#pragma unroll
    for (int e = 0; e < 8; ++e) cwv[e] = *(const float4*)&cw[(d0 + e) * 4];
#pragma unroll
    for (int e = 0; e < 8; e += 4) {
        float4 c = *(const float4*)&cb[d0 + e];
        cbv[e] = c.x; cbv[e + 1] = c.y; cbv[e + 2] = c.z; cbv[e + 3] = c.w;
    }
    u16x8 w0, w1, w2;
    if (lc == 0) {
        w0 = (u16x8)0; w1 = (u16x8)0; w2 = (u16x8)0;
    } else {
        w0 = *(const u16x8*)&xin[(size_t)(row0 - 3) * (2 * DINNER) + d0];
        w1 = *(const u16x8*)&xin[(size_t)(row0 - 2) * (2 * DINNER) + d0];
        w2 = *(const u16x8*)&xin[(size_t)(row0 - 1) * (2 * DINNER) + d0];
    }
    float sums[16];
#pragma unroll
    for (int t = 0; t < 16; ++t) {
        u16x8 cur = *(const u16x8*)&xin[(size_t)(row0 + t) * (2 * DINNER) + d0];
        float lsum = 0.f;
        u16x8 o;
#pragma unroll
        for (int e = 0; e < 8; ++e) {
            float acc = cbv[e];
            acc += bf2f(w0[e]) * cwv[e].x;
            acc += bf2f(w1[e]) * cwv[e].y;
            acc += bf2f(w2[e]) * cwv[e].z;
            acc += bf2f(cur[e]) * cwv[e].w;
            float s = silu_f(acc);
            lsum += s;
            o[e] = f2bf(s);
        }
        *(u16x8*)&xconv[(size_t)(row0 + t) * DINNER + d0] = o;
        sums[t] = lsum;
        w0 = w1; w1 = w2; w2 = cur;
    }
#pragma unroll
    for (int off = 32; off; off >>= 1)
#pragma unroll
        for (int t = 0; t < 16; ++t) sums[t] += __shfl_down(sums[t], off);
    __shared__ float wred[4][16];
    if (lane == 0) {
#pragma unroll
        for (int t = 0; t < 16; ++t) wred[wave][t] = sums[t];
    }
    __syncthreads();
    if (tid < 16)
        xavg[row0 + tid] = (wred[0][tid] + wred[1][tid] + wred[2][tid] + wred[3][tid]) *
                           (1.f / DINNER);
}

// delta/B/C projections: thin GEMM (8192 x 48 x 2048), K split across waves.
__global__ __launch_bounds__(256) void dbc_direct(
    const u16* __restrict__ xconv, const u16* __restrict__ wcat,
    const float* __restrict__ db, const float* __restrict__ A_log,
    const float* __restrict__ xavg,
    float* __restrict__ a_out, float* __restrict__ u_out, float* __restrict__ c_out) {
    __shared__ float part[4][32][48];
    const int tid = threadIdx.x;
    const int lane = tid & 63;
    const int wave = tid >> 6;
    const int bm = blockIdx.x * 32;
    const int fr = lane & 15;
    const int kq = lane >> 4;
    const int k0 = wave * 512 + kq * 8;

    const u16* ap0 = xconv + (size_t)(bm + fr) * DINNER + k0;
    const u16* ap1 = xconv + (size_t)(bm + 16 + fr) * DINNER + k0;
    const u16* bp0 = wcat + (size_t)(fr) * DINNER + k0;
    const u16* bp1 = wcat + (size_t)(16 + fr) * DINNER + k0;
    const u16* bp2 = wcat + (size_t)(32 + fr) * DINNER + k0;

    floatx4 acc[2][3];
#pragma unroll
    for (int mi = 0; mi < 2; ++mi)
#pragma unroll
        for (int ni = 0; ni < 3; ++ni) acc[mi][ni] = (floatx4){0.f, 0.f, 0.f, 0.f};

#pragma unroll 4
    for (int kk = 0; kk < 16; ++kk) {
        short8 a0 = *(const short8*)ap0;
        short8 a1 = *(const short8*)ap1;
        short8 b0 = *(const short8*)bp0;
        short8 b1 = *(const short8*)bp1;
        short8 b2 = *(const short8*)bp2;
        ap0 += 32; ap1 += 32; bp0 += 32; bp1 += 32; bp2 += 32;
        acc[0][0] = __builtin_amdgcn_mfma_f32_16x16x32_bf16(a0, b0, acc[0][0], 0, 0, 0);
        acc[0][1] = __builtin_amdgcn_mfma_f32_16x16x32_bf16(a0, b1, acc[0][1], 0, 0, 0);
        acc[0][2] = __builtin_amdgcn_mfma_f32_16x16x32_bf16(a0, b2, acc[0][2], 0, 0, 0);
        acc[1][0] = __builtin_amdgcn_mfma_f32_16x16x32_bf16(a1, b0, acc[1][0], 0, 0, 0);
        acc[1][1] = __builtin_amdgcn_mfma_f32_16x16x32_bf16(a1, b1, acc[1][1], 0, 0, 0);
        acc[1][2] = __builtin_amdgcn_mfma_f32_16x16x32_bf16(a1, b2, acc[1][2], 0, 0, 0);
    }
    // C/D 16x16 layout: col = lane&15, row = (lane>>4)*4 + r
    const int cr = kq * 4;
#pragma unroll
    for (int mi = 0; mi < 2; ++mi)
#pragma unroll
        for (int ni = 0; ni < 3; ++ni)
#pragma unroll
            for (int r = 0; r < 4; ++r)
                part[wave][mi * 16 + cr + r][ni * 16 + fr] = acc[mi][ni][r];
    __syncthreads();
#pragma unroll
    for (int it = tid; it < 512; it += 256) {
        int row = it >> 4;
        int s = it & 15;
        float sd = 0.f, sb = 0.f, sc = 0.f;
#pragma unroll
        for (int w = 0; w < 4; ++w) {
            sd += part[w][row][s];
            sb += part[w][row][s + 16];
            sc += part[w][row][s + 32];
        }
        int grow = bm + row;
        float Aa = -__expf(A_log[s]);
        float pre = sd + db[s];
        float delta = (pre > 20.f) ? pre : log1pf(__expf(pre));
        a_out[grow * NSTATE + s] = __expf(delta * Aa);
        u_out[grow * NSTATE + s] = delta * sb * xavg[grow];
        c_out[grow * NSTATE + s] = sc;
    }
}

// ---- fused parallel linear scan: one kernel, 4 blocks (one per batch) ----
// threads: 1024 = 64 segs x 16 states. p1 in-reg; p2 serial in LDS by 16
// threads; p3 rescan + cross-state shfl reduce. Same op order as the
// 3-kernel version (bit-identical math).
__global__ __launch_bounds__(1024) void scan_fused(
    const float* __restrict__ a, const float* __restrict__ u,
    const float* __restrict__ c, float* __restrict__ y) {
    const int b = blockIdx.x;
    const int tid = threadIdx.x;
    const int s = tid & 15;
    const int seg = tid >> 4;   // 0..63
    __shared__ float Ps[NSEG][NSTATE];
    __shared__ float Hs[NSEG][NSTATE];
    __shared__ float HSs[NSEG][NSTATE];

    size_t base = (size_t)(b * LL + seg * SEGLEN) * NSTATE + s;
    float P = 1.f, h = 0.f;
#pragma unroll 8
    for (int t = 0; t < SEGLEN; ++t) {
        float av = a[base + (size_t)t * NSTATE];
        float uv = u[base + (size_t)t * NSTATE];
        h = fmaf(av, h, uv);
        P *= av;
    }
    Ps[seg][s] = P;
    Hs[seg][s] = h;
    __syncthreads();
    if (tid < 16) {
        float hh = 0.f;
        for (int g = 0; g < NSEG; ++g) {
            HSs[g][tid] = hh;
            hh = fmaf(Ps[g][tid], hh, Hs[g][tid]);
        }
    }
    __syncthreads();
    float h2 = HSs[seg][s];
#pragma unroll 8
    for (int t = 0; t < SEGLEN; ++t) {
        float av = a[base + (size_t)t * NSTATE];
        float uv = u[base + (size_t)t * NSTATE];
        float cv = c[base + (size_t)t * NSTATE];
        h2 = fmaf(av, h2, uv);
        float p = h2 * cv;
        p += __shfl_xor(p, 1);
        p += __shfl_xor(p, 2);
        p += __shfl_xor(p, 4);
        p += __shfl_xor(p, 8);
        if (s == 0) y[b * LL + seg * SEGLEN + t] = p;
    }
}

// y_skip = y*silu(x_gate) + x_conv*D  -> bf16
__global__ __launch_bounds__(256) void gate_skip(
    const u16* __restrict__ xin, const float* __restrict__ y,
    const float* __restrict__ Dv, const u16* __restrict__ xconv,
    u16* __restrict__ yskip) {
    size_t i = ((size_t)blockIdx.x * 256 + threadIdx.x) * 8;
    int row = (int)(i >> 11);
    int d = (int)(i & (DINNER - 1));
    u16x8 g = *(const u16x8*)&xin[(size_t)row * (2 * DINNER) + DINNER + d];
    u16x8 xc = *(const u16x8*)&xconv[i];
    float yv = y[row];
    u16x8 o;
#pragma unroll
    for (int e = 0; e < 8; ++e) {
        float gv = silu_f(bf2f(g[e]));
        float v = yv * gv + bf2f(xc[e]) * Dv[d + e];
        o[e] = f2bf(v);
    }
    *(u16x8*)&yskip[i] = o;
}

extern "C" void kernel_launch(void* const* d_in, const int* in_sizes, int n_in,
                              void* d_out, int out_size, void* d_ws, size_t ws_size,
                              hipStream_t stream) {
    const float* x       = (const float*)d_in[0];
    const float* w_in    = (const float*)d_in[1];
    const float* conv_w  = (const float*)d_in[2];
    const float* conv_b  = (const float*)d_in[3];
    const float* A_log   = (const float*)d_in[4];
    const float* Dv      = (const float*)d_in[5];
    const float* delta_w = (const float*)d_in[6];
    const float* delta_b = (const float*)d_in[7];
    const float* B_w     = (const float*)d_in[8];
    const float* C_w     = (const float*)d_in[9];
    const float* out_w   = (const float*)d_in[10];
    float* out = (float*)d_out;

    u16* xb  = (u16*)d_ws;                 // 8192*1024
    u16* wb  = xb + 8388608;               // 4096*1024
    u16* owb = wb + 4194304;               // 1024*2048
    u16* wsb = owb + 2097152;              // 48*2048 (concat dw,bw,cw)
    u16* xin = wsb + 98304;                // 8192*4096
    u16* xcv = xin + 33554432;             // 8192*2048
    u16* ysk = xcv + 16777216;             // 8192*2048
    float* fb     = (float*)(ysk + 16777216);
    float* abuf   = fb;                    // 8192*16
    float* ubuf   = abuf + 131072;
    float* cbuf   = ubuf + 131072;
    float* ybuf   = cbuf + 131072;         // 8192
    float* avgbuf = ybuf + 8192;           // 8192

    cvt_multi<<<7216, 256, 0, stream>>>(x, w_in, out_w, delta_w, B_w, C_w,
                                        xb, wb, owb, wsb, wsb + 32768, wsb + 65536);

    // x_inner = x @ in_proj_w.T : (8192x1024)@(4096x1024)^T -> bf16
    gemm_bt_256<1><<<dim3(16, 32), 512, 0, stream>>>(xb, wb, xin, 2 * DINNER, DMODEL);

    conv_silu_avg<<<512, 256, 0, stream>>>(xin, conv_w, conv_b, xcv, avgbuf);
    dbc_direct<<<256, 256, 0, stream>>>(xcv, wsb, delta_b, A_log, avgbuf,
                                        abuf, ubuf, cbuf);

    scan_fused<<<4, 1024, 0, stream>>>(abuf, ubuf, cbuf, ybuf);

    gate_skip<<<NROW * DINNER / 8 / 256, 256, 0, stream>>>(xin, ybuf, Dv, xcv, ysk);

    // out = y_skip @ out_proj_w.T : (8192x2048)@(1024x2048)^T -> fp32
    gemm_bt_mfma<0><<<dim3(8, 64), 256, 0, stream>>>(ysk, owb, out, DMODEL, DINNER);
}